// Round 19
// baseline (427.998 us; speedup 1.0000x reference)
//
#include <hip/hip_runtime.h>
#include <cstddef>
#include <cstdint>

// Problem constants
#define QN   200
#define DIM  512
#define NHEAD 8
#define HD   64
#define C2   256
#define NH2  4
#define NTOK 4096   // 64*64

typedef unsigned short ushort_t;
typedef unsigned int u32;
typedef short s16x4 __attribute__((ext_vector_type(4)));
typedef short s16x8 __attribute__((ext_vector_type(8)));   // 8 bf16 (4 VGPRs)
typedef float f32x4 __attribute__((ext_vector_type(4)));   // MFMA accumulator

__device__ __forceinline__ unsigned short f2bf(float f) {
    unsigned int u = __float_as_uint(f);
    u += 0x7fffu + ((u >> 16) & 1u);   // round-to-nearest-even
    return (unsigned short)(u >> 16);
}
__device__ __forceinline__ float bf2f(unsigned short u) {
    return __uint_as_float(((unsigned int)u) << 16);
}
__device__ __forceinline__ s16x8 pack8(float4 x, float4 y) {
    s16x8 v;
    v[0] = (short)f2bf(x.x); v[1] = (short)f2bf(x.y);
    v[2] = (short)f2bf(x.z); v[3] = (short)f2bf(x.w);
    v[4] = (short)f2bf(y.x); v[5] = (short)f2bf(y.y);
    v[6] = (short)f2bf(y.z); v[7] = (short)f2bf(y.w);
    return v;
}

// global -> LDS 16B DMA (wave-uniform LDS base + lane*16)
__device__ __forceinline__ void gld16(const ushort_t* g, short* l) {
    __builtin_amdgcn_global_load_lds(
        (const __attribute__((address_space(1))) u32*)g,
        (__attribute__((address_space(3))) u32*)l, 16, 0, 0);
}

// ---------------------------------------------------------------------------
// Merged: all fp32->bf16 conversions (9 jobs, blocks [0,17296)) +
// all 4 conv-weight transposes (blocks [17296,19344)).
// wtrans: w (512, 512, KK) fp32 -> wt (512, KK*512) bf16, k'=p*512+ci
// ---------------------------------------------------------------------------
struct CDesc { const float* s; ushort_t* d; };
struct CPack { CDesc c[9]; int bound[9]; };
struct WDesc { const float* s; ushort_t* d; int KK; int lKK; };
struct WPack { WDesc w[4]; };
__global__ __launch_bounds__(256) void cvt_wtrans(CPack pk, WPack wp)
{
    __shared__ float tile[512 * 17];
    int bid = blockIdx.x;
    if (bid < 17296) {
        int idx = 0;
#pragma unroll
        for (int i = 0; i < 8; ++i) idx += (bid >= pk.bound[i]);
        const int base = idx ? pk.bound[idx - 1] : 0;
        const int i = (bid - base) * 256 + threadIdx.x;
        const float4 a = ((const float4*)pk.c[idx].s)[i * 2];
        const float4 b = ((const float4*)pk.c[idx].s)[i * 2 + 1];
        ((s16x8*)pk.c[idx].d)[i] = pack8(a, b);
        return;
    }
    bid -= 17296;
    const WDesc d = wp.w[bid >> 9];
    const int c = bid & 511;
    const int KK = d.KK, lKK = d.lKK;
    const int K = KK << 9;
    const float* src = d.s + (size_t)c * K;
    ushort_t* dst = d.d + (size_t)c * K;
    for (int i = threadIdx.x; i < K; i += 256) {
        int ci = i >> lKK, p = i & (KK - 1);
        tile[ci * (KK + 1) + p] = src[i];
    }
    __syncthreads();
    for (int i = threadIdx.x; i < K; i += 256) {
        int p = i >> 9, ci = i & 511;
        dst[i] = f2bf(tile[ci * (KK + 1) + p]);
    }
}

// ---------------------------------------------------------------------------
// Conv-patch GEMM (MFMA bf16, A bf16 image): C = gather(A)(M,K) * B(512,K)^T
// 128x128 tile, BK=64, global_load_lds(16B) staging.
// T3+T4: double-buffered LDS with COUNTED-vmcnt barriers (ROUND-14 VERIFIED
// ARTIFACT: 82.5us). stage(t+1) issued before compute(t); barrier #1 waits
// only vmcnt(8); raw s_barrier (no full drain). Epilogue drains vmcnt(0).
// sched_barrier(0) pins frag reads between the barriers (rule #18).
// [round-10 retile 128x64 REGRESSED: occupancy not binding.]
// [round-18 asym depth-2 A REGRESSED: gather latency not the residual stall;
//  2-barrier structure is at its ceiling ~82us.]
// XOR swizzle on the SOURCE address; fragment reads use matching swizzle.
// 4 jobs merged, 256 blocks each (uniform 32 K-iters/block):
//   conv1-K, conv1-V (M=2048, K=8192, split-K z=4)
//   conv2-K, conv2-V (M=8192, K=2048, z=1)
// Within a job: xcd=loc&7, j=loc>>3, nt=j&3, mz=(j>>2)*8+xcd,
// mt=mz&(2^lMT-1), z=mz>>lMT. klen fixed at 2048 (kstart = z<<11).
// fp32 partials at C + z*M*512 (bias/reduction fused into LN).
// ---------------------------------------------------------------------------
struct GDesc { const ushort_t* A; const ushort_t* B; float* C;
               int M; int K; int lOW; int ls; int lMT; };
struct GPack { GDesc g[4]; };
__global__ __launch_bounds__(256) void conv_gemm(GPack pk)
{
    // double buffer: buf b at lds + b*16384 shorts; within buf: A [0,8192), B [8192,16384)
    __shared__ short lds[32768];

    const int tid = threadIdx.x;
    const int bid = blockIdx.x;
    const GDesc gd = pk.g[bid >> 8];
    const ushort_t* Ap = gd.A;
    const ushort_t* Bp = gd.B;
    float* Cp = gd.C;
    const int M = gd.M, K = gd.K, lOW = gd.lOW, ls = gd.ls, lMT = gd.lMT;

    const int loc = bid & 255;
    const int xcd = loc & 7;
    const int j = loc >> 3;
    const int nt = j & 3;
    const int mz = (j >> 2) * 8 + xcd;
    const int mt = mz & ((1 << lMT) - 1);
    const int z = mz >> lMT;
    const int m0 = mt * 128, n0 = nt * 128;
    const int kstart = z << 11;   // klen = 2048

    const int lane = tid & 63, wave = tid >> 6;
    const int l16 = lane & 15, quad = lane >> 4;
    const int wm = (wave >> 1) * 64;
    const int wn = (wave & 1) * 64;

    // staging maps: slot g covers LDS 16B-block g; content row g>>3,
    // k-block (g&7)^(row&7) (source-side swizzle)
    unsigned abase[4]; int acb[4];
    const ushort_t* bptr[4];
    short* ldsA[4]; short* ldsB[4];
    const int OW = 1 << lOW;
#pragma unroll
    for (int i = 0; i < 4; ++i) {
        const int g = i * 256 + tid;
        const int r = g >> 3, c = g & 7;
        acb[i] = ((c ^ (r & 7)) << 3);
        const int m = m0 + r;
        const int bidx = m >> (2 * lOW);
        const int pix = m & (OW * OW - 1);
        const int oy = pix >> lOW, ox = pix & (OW - 1);
        abase[i] = (unsigned)(bidx * NTOK + (oy << ls) * 64 + (ox << ls)) << 9;
        bptr[i] = Bp + (unsigned)(n0 + r) * K + kstart + acb[i];
        ldsA[i] = lds + (i * 256 + wave * 64) * 8;
        ldsB[i] = lds + 8192 + (i * 256 + wave * 64) * 8;
    }

    f32x4 acc[4][4];
#pragma unroll
    for (int a = 0; a < 4; ++a)
#pragma unroll
        for (int b = 0; b < 4; ++b)
            acc[a][b] = (f32x4){0.f, 0.f, 0.f, 0.f};

    const int lsm = (1 << ls) - 1;

    // stage tile t into buffer b (8 x 16B DMA per thread)
    auto stage = [&](int t, int b) {
        const int k0 = kstart + (t << 6);
        const int boff = b << 14;   // 16384 shorts
#pragma unroll
        for (int i = 0; i < 4; ++i) {
            const int k = k0 + acb[i];
            const int p = k >> 9;
            const int ky = p >> ls, kx = p & lsm;
            gld16(Ap + abase[i] + ((unsigned)(ky * 64 + kx) << 9) + (k & 511),
                  ldsA[i] + boff);
            gld16(bptr[i] + (t << 6), ldsB[i] + boff);
        }
    };

    stage(0, 0);   // 8 DMAs in flight
#pragma unroll 1
    for (int t = 0; t < 32; ++t) {
        if (t + 1 < 32) {
            stage(t + 1, (t + 1) & 1);   // +8 DMAs -> 16 in flight
            // wait only for stage(t)'s 8 (oldest); stage(t+1)'s fly on
            asm volatile("s_waitcnt vmcnt(8)" ::: "memory");
        } else {
            asm volatile("s_waitcnt vmcnt(0)" ::: "memory");
        }
        __builtin_amdgcn_sched_barrier(0);   // no frag reads above this point
        __builtin_amdgcn_s_barrier();        // stage(t) visible to all waves

        const short* Abuf = lds + ((t & 1) << 14);
        const short* Bbuf = Abuf + 8192;
#pragma unroll
        for (int kk = 0; kk < 2; ++kk) {
            const int sw = ((quad + kk * 4) ^ (l16 & 7)) << 3;
            s16x8 af[4], bfv[4];
#pragma unroll
            for (int f = 0; f < 4; ++f)
                af[f] = *(const s16x8*)&Abuf[(wm + f * 16 + l16) * 64 + sw];
#pragma unroll
            for (int f = 0; f < 4; ++f)
                bfv[f] = *(const s16x8*)&Bbuf[(wn + f * 16 + l16) * 64 + sw];
#pragma unroll
            for (int a = 0; a < 4; ++a)
#pragma unroll
                for (int b = 0; b < 4; ++b)
                    acc[a][b] = __builtin_amdgcn_mfma_f32_16x16x32_bf16(
                        af[a], bfv[b], acc[a][b], 0, 0, 0);
        }
        __builtin_amdgcn_sched_barrier(0);   // all frag reads of buf t above
        __builtin_amdgcn_s_barrier();        // before t+1 issues stage(t+2) into buf t
        asm volatile("" ::: "memory");
    }

    float* __restrict__ Cz = Cp + (size_t)z * M * 512;
#pragma unroll
    for (int a = 0; a < 4; ++a) {
        const int m = m0 + wm + a * 16 + quad * 4;
#pragma unroll
        for (int b = 0; b < 4; ++b) {
            const int n = n0 + wn + b * 16 + l16;
#pragma unroll
            for (int r = 0; r < 4; ++r)
                Cz[(unsigned)(m + r) * 512 + n] = acc[a][b][r];
        }
    }
}

// ---------------------------------------------------------------------------
// 64x64-tile, K=512 GEMM body (bf16 in; OBF 1: bf16 out, 0: fp32 out + bias)
// ---------------------------------------------------------------------------
template <int OBF>
__device__ __forceinline__ void gemm64_k512(
    short* lds, const ushort_t* __restrict__ Ab, const ushort_t* __restrict__ Bp,
    const float* __restrict__ bias, void* __restrict__ Cp_,
    int m0, int n0, int N, float oscale)
{
    const int tid = threadIdx.x;
    const int lane = tid & 63, wave = tid >> 6;
    const int l16 = lane & 15, quad = lane >> 4;
    const int wm = (wave >> 1) * 32;
    const int wn = (wave & 1) * 32;

    auto off = [](int r, int c) -> int {
        return ((r >> 1) << 6) + (((((r & 1) << 2) | c) ^ ((r >> 1) & 7)) << 3);
    };

    const int cs = (tid & 3) * 8;
    const int ofA = off(tid >> 2, tid & 3);
    const unsigned ab = (unsigned)(m0 + (tid >> 2)) * 512;
    const unsigned bb = (unsigned)(n0 + (tid >> 2)) * 512;

    s16x8 aR, bR;
    auto loadg = [&](int t) {
        aR = *(const s16x8*)(Ab + ab + t * 32 + cs);
        bR = *(const s16x8*)(Bp + bb + t * 32 + cs);
    };
    auto stg = [&](int buf) {
        short* A = lds + buf * 4096;
        short* Bs = A + 2048;
        *(s16x8*)&A[ofA] = aR;
        *(s16x8*)&Bs[ofA] = bR;
    };

    f32x4 acc[2][2];
#pragma unroll
    for (int a = 0; a < 2; ++a)
#pragma unroll
        for (int b = 0; b < 2; ++b)
            acc[a][b] = (f32x4){0.f, 0.f, 0.f, 0.f};

    loadg(0); stg(0); __syncthreads();
#pragma unroll 1
    for (int t = 0; t < 16; ++t) {
        if (t + 1 < 16) loadg(t + 1);
        const short* A = lds + (t & 1) * 4096;
        const short* Bs = A + 2048;
        s16x8 af[2], bfv[2];
#pragma unroll
        for (int f = 0; f < 2; ++f)
            af[f] = *(const s16x8*)&A[off(wm + f * 16 + l16, quad)];
#pragma unroll
        for (int f = 0; f < 2; ++f)
            bfv[f] = *(const s16x8*)&Bs[off(wn + f * 16 + l16, quad)];
#pragma unroll
        for (int a = 0; a < 2; ++a)
#pragma unroll
            for (int b = 0; b < 2; ++b)
                acc[a][b] = __builtin_amdgcn_mfma_f32_16x16x32_bf16(
                    af[a], bfv[b], acc[a][b], 0, 0, 0);
        if (t + 1 < 16) { stg((t + 1) & 1); __syncthreads(); }
    }

#pragma unroll
    for (int a = 0; a < 2; ++a) {
        const int m = m0 + wm + a * 16 + quad * 4;
#pragma unroll
        for (int b = 0; b < 2; ++b) {
            const int n = n0 + wn + b * 16 + l16;
            const float bv = bias ? bias[n] : 0.f;
#pragma unroll
            for (int r = 0; r < 4; ++r) {
                const float val = acc[a][b][r] * oscale + bv;
                if constexpr (OBF)
                    ((ushort_t*)Cp_)[(unsigned)(m + r) * N + n] = f2bf(val);
                else
                    ((float*)Cp_)[(unsigned)(m + r) * N + n] = val;
            }
        }
    }
}

// Merged q/k1/v1/k2/v2 projections (one launch, 1480 blocks)
struct PDesc { const ushort_t* A; const ushort_t* B; ushort_t* C; int lnT; float scale; };
struct PPack { PDesc d[5]; int bound[5]; };
__global__ __launch_bounds__(256) void proj_gemm(PPack pk)
{
    __shared__ short lds[8192];
    const int bid = blockIdx.x;
    int idx = 0;
#pragma unroll
    for (int i = 0; i < 4; ++i) idx += (bid >= pk.bound[i]);
    const PDesc d = pk.d[idx];
    const int base = idx ? pk.bound[idx - 1] : 0;
    const int loc = bid - base;
    const int nt = loc & ((1 << d.lnT) - 1);
    const int mt = loc >> d.lnT;
    gemm64_k512<1>(lds, d.A, d.B, nullptr, d.C, mt * 64, nt * 64, 64 << d.lnT, d.scale);
}

// Final projection: fp32 out + bias, 200 blocks
__global__ __launch_bounds__(256) void final_gemm(
    const ushort_t* __restrict__ A, const ushort_t* __restrict__ B,
    const float* __restrict__ bias, float* __restrict__ C)
{
    __shared__ short lds[8192];
    const int m0 = (blockIdx.x >> 3) * 64;
    const int n0 = (blockIdx.x & 7) * 64;
    gemm64_k512<0>(lds, A, B, bias, C, m0, n0, 512, 1.0f);
}

// ---------------------------------------------------------------------------
// LayerNorm + ReLU6 with fused split-K reduction + conv bias; all 4 jobs
// (key1, val1, key2, val2) in one launch. dst bf16.
// ---------------------------------------------------------------------------
struct LDesc { ushort_t* d; const float* s; const float* cb;
               const float* g; const float* b; unsigned pstride; int np; };
struct LPack { LDesc l[4]; int bound[4]; };
__global__ __launch_bounds__(256) void ln_all(LPack pk)
{
    const int bid = blockIdx.x;
    int idx = 0;
#pragma unroll
    for (int i = 0; i < 3; ++i) idx += (bid >= pk.bound[i]);
    const LDesc d = pk.l[idx];
    const int base = idx ? pk.bound[idx - 1] : 0;
    const int blk = bid - base;
    const int row = blk * 4 + (threadIdx.x >> 6);
    const int lane = threadIdx.x & 63;
    float v[8];
#pragma unroll
    for (int j = 0; j < 8; ++j) v[j] = d.cb[lane + 64 * j];
    const float* p = d.s + (size_t)row * DIM;
    for (int ip = 0; ip < d.np; ++ip) {
#pragma unroll
        for (int j = 0; j < 8; ++j) v[j] += p[lane + 64 * j];
        p += d.pstride;
    }
    float s1v = 0.f, s2v = 0.f;
#pragma unroll
    for (int j = 0; j < 8; ++j) { s1v += v[j]; s2v += v[j] * v[j]; }
#pragma unroll
    for (int off = 32; off; off >>= 1) {
        s1v += __shfl_xor(s1v, off, 64);
        s2v += __shfl_xor(s2v, off, 64);
    }
    const float mean = s1v * (1.0f / DIM);
    const float var = s2v * (1.0f / DIM) - mean * mean;
    const float rstd = rsqrtf(var + 1e-5f);
    ushort_t* q = d.d + (size_t)row * DIM;
#pragma unroll
    for (int j = 0; j < 8; ++j) {
        const int c = lane + 64 * j;
        float y = (v[j] - mean) * rstd * d.g[c] + d.b[c];
        q[c] = f2bf(fminf(fmaxf(y, 0.0f), 6.0f));
    }
}

// ---------------------------------------------------------------------------
// vplus = v + dwconv3x3 + bias, both branches in one launch
// ---------------------------------------------------------------------------
__device__ __forceinline__ void vplus_body(
    const ushort_t* __restrict__ vbuf, const float* __restrict__ lw,
    const float* __restrict__ lb, ushort_t* __restrict__ out,
    int lOW, int lL, int blk)
{
    const int idx = blk * 256 + threadIdx.x;
    const int c = idx & 255;
    const int pix = (idx >> 8) & ((1 << lL) - 1);
    const int b = idx >> (8 + lL);
    const int OW = 1 << lOW;
    const int y = pix >> lOW, x = pix & (OW - 1);
    float acc = lb[c];
#pragma unroll
    for (int dy = -1; dy <= 1; ++dy) {
        const int ny = y + dy;
        if ((unsigned)ny >= (unsigned)OW) continue;
#pragma unroll
        for (int dx = -1; dx <= 1; ++dx) {
            const int nx = x + dx;
            if ((unsigned)nx >= (unsigned)OW) continue;
            acc += bf2f(vbuf[(((unsigned)(b << lL) + ny * OW + nx) << 8) + c]) *
                   lw[c * 9 + (dy + 1) * 3 + (dx + 1)];
        }
    }
    out[idx] = f2bf(bf2f(vbuf[idx]) + acc);
}

__global__ __launch_bounds__(256) void vplus2_kernel(
    const ushort_t* v1, const float* w1, const float* b1, ushort_t* o1,
    const ushort_t* v2, const float* w2, const float* b2, ushort_t* o2)
{
    const int bid = blockIdx.x;
    if (bid < 2048) vplus_body(v1, w1, b1, o1, 4, 8, bid);
    else            vplus_body(v2, w2, b2, o2, 5, 10, bid - 2048);
}

// ---------------------------------------------------------------------------
// MFMA attention, all operands bf16 (Q pre-scaled by 0.125 in q-projection).
// Both branches merged into one launch: grid z in [0,8) = branch1 (L=256),
// [8,16) = branch2 (L=1024). Static 77,888B LDS (2 blocks/CU).
// WAVE-PRIVATE K/V staging (round-12, verified): phases A and C barrier-free
// via same-wave DS ordering. T5: s_setprio(1) around the MFMA clusters —
// waves here are at DIFFERENT phases (no lockstep barriers), so the CU
// scheduler can prefer MFMA-issuing waves over load-issuing ones.
// ---------------------------------------------------------------------------
template <int L>
__device__ __forceinline__ void attn_body(
    char* smem,
    const ushort_t* __restrict__ qbuf, const ushort_t* __restrict__ kbuf,
    const ushort_t* __restrict__ vbuf, ushort_t* __restrict__ xbuf,
    const int hoff, const int coff, const int b)
{
    constexpr int SP = L + 12;
    constexpr int NV = L / 64;
    float (*S)[SP]   = (float (*)[SP])smem;                       // 16*SP*4 B
    float* invs      = (float*)(smem + 64 * SP);                  // 64 B
    short (*Qs)[72]  = (short (*)[72])(smem + 64 * SP + 64);      // 2304 B
    short (*KV)[72]  = (short (*)[72])(smem + 64 * SP + 64 + 2304); // 9216 B

    const int tid = threadIdx.x;
    const int qt = blockIdx.x;
    const int h = blockIdx.y;
    const int lane = tid & 63, wave = tid >> 6;
    const int l16 = lane & 15, quad = lane >> 4;

    {
        const int r = tid >> 4, d0 = (tid & 15) * 4;
        int qi = qt * 16 + r; if (qi > QN - 1) qi = QN - 1;
        *(s16x4*)&Qs[r][d0] = *(const s16x4*)(
            qbuf + ((unsigned)(b * QN + qi) * NHEAD + hoff + h) * HD + d0);
    }
    __syncthreads();   // publish Qs (phase A itself needs no barriers)

    // Q fragments are loop-invariant: hoist once.
    s16x8 qf[2];
#pragma unroll
    for (int c = 0; c < 2; ++c)
        qf[c] = *(const s16x8*)&Qs[l16][c * 32 + quad * 8];

    // ---- Phase A: S = Q K^T ---- (KV rows wave-private; no barriers)
    const int klr = tid >> 2, kd0 = (tid & 3) * 16;
    for (int l0 = 0; l0 < L; l0 += 64) {
        const unsigned src = (unsigned)(b * L + l0 + klr) * C2 + h * HD + kd0;
        const s16x8 x0 = *(const s16x8*)(kbuf + src);
        const s16x8 x1 = *(const s16x8*)(kbuf + src + 8);
        *(s16x8*)&KV[klr][kd0] = x0;
        *(s16x8*)&KV[klr][kd0 + 8] = x1;
        f32x4 sacc = (f32x4){0.f, 0.f, 0.f, 0.f};
        __builtin_amdgcn_s_setprio(1);
#pragma unroll
        for (int c = 0; c < 2; ++c) {
            const s16x8 bf = *(const s16x8*)&KV[wave * 16 + l16][c * 32 + quad * 8];
            sacc = __builtin_amdgcn_mfma_f32_16x16x32_bf16(qf[c], bf, sacc, 0, 0, 0);
        }
        __builtin_amdgcn_s_setprio(0);
        const int col = l0 + wave * 16 + l16;
#pragma unroll
        for (int r = 0; r < 4; ++r) S[quad * 4 + r][col] = sacc[r];
    }
    __syncthreads();   // publish S for softmax

    // ---- Phase B: softmax ---- (rows wave-private)
#pragma unroll
    for (int rr = 0; rr < 4; ++rr) {
        const int row = wave * 4 + rr;
        float v[NV];
#pragma unroll
        for (int k = 0; k < NV; ++k) v[k] = S[row][lane + 64 * k];
        float m = -1e30f;
#pragma unroll
        for (int k = 0; k < NV; ++k) m = fmaxf(m, v[k]);
#pragma unroll
        for (int off = 32; off; off >>= 1) m = fmaxf(m, __shfl_xor(m, off, 64));
        float s = 0.f;
#pragma unroll
        for (int k = 0; k < NV; ++k) {
            v[k] = __expf(v[k] - m);
            s += v[k];
        }
#pragma unroll
        for (int off = 32; off; off >>= 1) s += __shfl_xor(s, off, 64);
#pragma unroll
        for (int k = 0; k < NV; ++k) S[row][lane + 64 * k] = v[k];
        if (lane == 0) invs[row] = 1.0f / s;
    }
    __syncthreads();   // publish softmax'd S + invs before PV

    // ---- Phase C: O = P V ---- (KV channel rows wave-private; no barriers)
    f32x4 oacc = (f32x4){0.f, 0.f, 0.f, 0.f};
    const int ctok = lane >> 2;                   // 0..15
    const int cd0 = wave * 16 + (lane & 3) * 4;   // wave-private channel base
    for (int l0 = 0; l0 < L; l0 += 64) {
#pragma unroll
        for (int p = 0; p < 4; ++p) {
            const int token = p * 16 + ctok;
            const s16x4 v = *(const s16x4*)(
                vbuf + (unsigned)(b * L + l0 + token) * C2 + h * HD + cd0);
            KV[cd0 + 0][token] = v[0];
            KV[cd0 + 1][token] = v[1];
            KV[cd0 + 2][token] = v[2];
            KV[cd0 + 3][token] = v[3];
        }
        __builtin_amdgcn_s_setprio(1);
#pragma unroll
        for (int c = 0; c < 2; ++c) {
            const float4 p0 = *(const float4*)&S[l16][l0 + c * 32 + quad * 8];
            const float4 p1 = *(const float4*)&S[l16][l0 + c * 32 + quad * 8 + 4];
            const s16x8 af = pack8(p0, p1);
            const s16x8 bf = *(const s16x8*)&KV[wave * 16 + l16][c * 32 + quad * 8];
            oacc = __builtin_amdgcn_mfma_f32_16x16x32_bf16(af, bf, oacc, 0, 0, 0);
        }
        __builtin_amdgcn_s_setprio(0);
    }

    const int dcol = wave * 16 + l16;
#pragma unroll
    for (int r = 0; r < 4; ++r) {
        const int q = quad * 4 + r;
        const int qi = qt * 16 + q;
        if (qi < QN) {
            const float val = oacc[r] * invs[q];
            const int flat = ((b * QN + qi) * NH2 + h) * HD + dcol;
            xbuf[(unsigned)(flat >> 8) * DIM + coff + (flat & 255)] = f2bf(val);
        }
    }
}

__global__ __launch_bounds__(256) void attn_both(
    const ushort_t* __restrict__ qbuf,
    const ushort_t* __restrict__ k1, const ushort_t* __restrict__ vp1,
    const ushort_t* __restrict__ k2, const ushort_t* __restrict__ vp2,
    ushort_t* __restrict__ xbuf)
{
    __shared__ char smem[77888] __attribute__((aligned(16)));
    const int bz = blockIdx.z;
    if (bz < 8) attn_body<256>(smem, qbuf, k1, vp1, xbuf, 0, 0, bz);
    else        attn_body<1024>(smem, qbuf, k2, vp2, xbuf, 4, 256, bz - 8);
}

// ---------------------------------------------------------------------------
// Launcher
// ---------------------------------------------------------------------------
extern "C" void kernel_launch(void* const* d_in, const int* in_sizes, int n_in,
                              void* d_out, int out_size, void* d_ws, size_t ws_size,
                              hipStream_t stream)
{
    const float* query   = (const float*)d_in[0];
    const float* key     = (const float*)d_in[1];
    const float* value   = (const float*)d_in[2];
    const float* q_w     = (const float*)d_in[3];
    const float* sr1_1_w = (const float*)d_in[4];
    const float* sr1_1_b = (const float*)d_in[5];
    const float* n1_1_g  = (const float*)d_in[6];
    const float* n1_1_b  = (const float*)d_in[7];
    const float* sr1_2_w = (const float*)d_in[8];
    const float* sr1_2_b = (const float*)d_in[9];
    const float* n1_2_g  = (const float*)d_in[10];
    const float* n1_2_b  = (const float*)d_in[11];
    const float* sr2_1_w = (const float*)d_in[12];
    const float* sr2_1_b = (const float*)d_in[13];
    const float* n2_1_g  = (const float*)d_in[14];
    const float* n2_1_b  = (const float*)d_in[15];
    const float* sr2_2_w = (const float*)d_in[16];
    const float* sr2_2_b = (const float*)d_in[17];
    const float* n2_2_g  = (const float*)d_in[18];
    const float* n2_2_b  = (const float*)d_in[19];
    const float* k1_w    = (const float*)d_in[20];
    const float* v1_w    = (const float*)d_in[21];
    const float* k2_w    = (const float*)d_in[22];
    const float* v2_w    = (const float*)d_in[23];
    const float* lc1_w   = (const float*)d_in[24];
    const float* lc1_b   = (const float*)d_in[25];
    const float* lc2_w   = (const float*)d_in[26];
    const float* lc2_b   = (const float*)d_in[27];
    const float* proj_w  = (const float*)d_in[28];
    const float* proj_b  = (const float*)d_in[29];
    float* out = (float*)d_out;
    char* ws = (char*)d_ws;

    // --- workspace layout (bytes); total ~199 MB (d_ws is 256 MiB) ---
    ushort_t* IMGK  = (ushort_t*)(ws + 0);            // 33.5 MB
    ushort_t* IMGV  = (ushort_t*)(ws + 33554432);     // 33.5 MB
    float*    SCRK1 = (float*)(ws + 67108864);        // 16.8 MB fp32 partials
    float*    SCRV1 = (float*)(ws + 83886080);        // 16.8 MB
    float*    SCRK2 = (float*)(ws + 100663296);       // 16.8 MB
    float*    SCRV2 = (float*)(ws + 117440512);       // 16.8 MB
    ushort_t* WT1K  = (ushort_t*)(ws + 134217728);    // 8.4 MB
    ushort_t* WT1V  = (ushort_t*)(ws + 142606336);    // 8.4 MB
    ushort_t* WT2K  = (ushort_t*)(ws + 150994944);    // 2.1 MB
    ushort_t* WT2V  = (ushort_t*)(ws + 153092096);    // 2.1 MB
    ushort_t* KEY1  = (ushort_t*)(ws + 155189248);    // 2.1 MB
    ushort_t* VAL1  = (ushort_t*)(ws + 157286400);
    ushort_t* KEY2  = (ushort_t*)(ws + 159383552);    // 8.4 MB
    ushort_t* VAL2  = (ushort_t*)(ws + 167772160);
    ushort_t* QRYB  = (ushort_t*)(ws + 176160768);    // 1600x512 bf16
    ushort_t* WQ    = (ushort_t*)(ws + 177799168);
    ushort_t* WK1   = (ushort_t*)(ws + 178323456);
    ushort_t* WV1   = (ushort_t*)(ws + 178585600);
    ushort_t* WK2   = (ushort_t*)(ws + 178847744);
    ushort_t* WV2   = (ushort_t*)(ws + 179109888);
    ushort_t* WP    = (ushort_t*)(ws + 179372032);
    ushort_t* QBUF  = (ushort_t*)(ws + 179896320);
    ushort_t* XBUF  = (ushort_t*)(ws + 181534720);
    ushort_t* K1    = (ushort_t*)(ws + 183173120);
    ushort_t* V1    = (ushort_t*)(ws + 184221696);
    ushort_t* VP1   = (ushort_t*)(ws + 185270272);
    ushort_t* K2    = (ushort_t*)(ws + 186318848);
    ushort_t* V2    = (ushort_t*)(ws + 190513152);
    ushort_t* VP2   = (ushort_t*)(ws + 194707456);    // ends 198,901,760

    // 1) all fp32->bf16 conversions + conv-weight transposes (one launch)
    CPack cp;
    cp.c[0] = {key,   IMGK}; cp.c[1] = {value, IMGV}; cp.c[2] = {query, QRYB};
    cp.c[3] = {q_w,   WQ};   cp.c[4] = {k1_w,  WK1};  cp.c[5] = {v1_w,  WV1};
    cp.c[6] = {k2_w,  WK2};  cp.c[7] = {v2_w,  WV2};  cp.c[8] = {proj_w, WP};
    cp.bound[0] = 8192;  cp.bound[1] = 16384; cp.bound[2] = 16784;
    cp.bound[3] = 16912; cp.bound[4] = 16976; cp.bound[5] = 17040;
    cp.bound[6] = 17104; cp.bound[7] = 17168; cp.bound[8] = 17296;
    WPack wp;
    wp.w[0] = {sr1_1_w, WT1K, 16, 4}; wp.w[1] = {sr1_2_w, WT1V, 16, 4};
    wp.w[2] = {sr2_1_w, WT2K, 4, 2};  wp.w[3] = {sr2_2_w, WT2V, 4, 2};
    cvt_wtrans<<<19344, 256, 0, stream>>>(cp, wp);

    // 2) all 4 conv GEMMs in one launch, uniform 256 blocks / 32 K-iters each
    //    conv1: split-K z=4 (klen=2048); conv2: z=1
    GPack gp;
    gp.g[0] = {IMGK, WT1K, SCRK1, 2048, 8192, 4, 2, 4};
    gp.g[1] = {IMGV, WT1V, SCRV1, 2048, 8192, 4, 2, 4};
    gp.g[2] = {IMGK, WT2K, SCRK2, 8192, 2048, 5, 1, 6};
    gp.g[3] = {IMGV, WT2V, SCRV2, 8192, 2048, 5, 1, 6};
    conv_gemm<<<1024, 256, 0, stream>>>(gp);

    // 3) all 4 LN+ReLU6 (+split-K reduce + conv bias) in one launch
    LPack lp;
    lp.l[0] = {KEY1, SCRK1, sr1_1_b, n1_1_g, n1_1_b, 1048576u, 4};
    lp.l[1] = {VAL1, SCRV1, sr1_2_b, n1_2_g, n1_2_b, 1048576u, 4};
    lp.l[2] = {KEY2, SCRK2, sr2_1_b, n2_1_g, n2_1_b, 4194304u, 1};
    lp.l[3] = {VAL2, SCRV2, sr2_2_b, n2_2_g, n2_2_b, 4194304u, 1};
    lp.bound[0] = 512; lp.bound[1] = 1024; lp.bound[2] = 3072; lp.bound[3] = 5120;
    ln_all<<<5120, 256, 0, stream>>>(lp);

    // 4) merged projections: q (scale 0.125 folded), k1, v1, k2, v2
    PPack pp;
    pp.d[0] = {QRYB, WQ,  QBUF, 3, 0.125f};
    pp.d[1] = {KEY1, WK1, K1,   2, 1.0f};
    pp.d[2] = {VAL1, WV1, V1,   2, 1.0f};
    pp.d[3] = {KEY2, WK2, K2,   2, 1.0f};
    pp.d[4] = {VAL2, WV2, V2,   2, 1.0f};
    pp.bound[0] = 200; pp.bound[1] = 328; pp.bound[2] = 456; pp.bound[3] = 968;
    pp.bound[4] = 1480;
    proj_gemm<<<1480, 256, 0, stream>>>(pp);

    // 5) v + local dwconv (both branches)
    vplus2_kernel<<<10240, 256, 0, stream>>>(V1, lc1_w, lc1_b, VP1,
                                             V2, lc2_w, lc2_b, VP2);

    // 6) attention, both branches in one launch (co-resident)
    attn_both<<<dim3(13, 4, 16), 256, 0, stream>>>(QBUF, K1, VP1, K2, VP2, XBUF);

    // 7) final projection + bias -> fp32 out
    final_gemm<<<200, 256, 0, stream>>>(XBUF, WP, proj_b, out);
}

// Round 20
// 419.997 us; speedup vs baseline: 1.0190x; 1.0190x over previous
//
#include <hip/hip_runtime.h>
#include <cstddef>
#include <cstdint>

// Problem constants
#define QN   200
#define DIM  512
#define NHEAD 8
#define HD   64
#define C2   256
#define NH2  4
#define NTOK 4096   // 64*64

typedef unsigned short ushort_t;
typedef unsigned int u32;
typedef short s16x4 __attribute__((ext_vector_type(4)));
typedef short s16x8 __attribute__((ext_vector_type(8)));   // 8 bf16 (4 VGPRs)
typedef float f32x4 __attribute__((ext_vector_type(4)));   // MFMA accumulator

__device__ __forceinline__ unsigned short f2bf(float f) {
    unsigned int u = __float_as_uint(f);
    u += 0x7fffu + ((u >> 16) & 1u);   // round-to-nearest-even
    return (unsigned short)(u >> 16);
}
__device__ __forceinline__ float bf2f(unsigned short u) {
    return __uint_as_float(((unsigned int)u) << 16);
}
__device__ __forceinline__ s16x8 pack8(float4 x, float4 y) {
    s16x8 v;
    v[0] = (short)f2bf(x.x); v[1] = (short)f2bf(x.y);
    v[2] = (short)f2bf(x.z); v[3] = (short)f2bf(x.w);
    v[4] = (short)f2bf(y.x); v[5] = (short)f2bf(y.y);
    v[6] = (short)f2bf(y.z); v[7] = (short)f2bf(y.w);
    return v;
}

// global -> LDS 16B DMA (wave-uniform LDS base + lane*16)
__device__ __forceinline__ void gld16(const ushort_t* g, short* l) {
    __builtin_amdgcn_global_load_lds(
        (const __attribute__((address_space(1))) u32*)g,
        (__attribute__((address_space(3))) u32*)l, 16, 0, 0);
}

// ---------------------------------------------------------------------------
// Merged: all fp32->bf16 conversions (9 jobs, blocks [0,17296)) +
// all 4 conv-weight transposes (blocks [17296,19344)).
// wtrans: w (512, 512, KK) fp32 -> wt (512, KK*512) bf16, k'=p*512+ci
// ---------------------------------------------------------------------------
struct CDesc { const float* s; ushort_t* d; };
struct CPack { CDesc c[9]; int bound[9]; };
struct WDesc { const float* s; ushort_t* d; int KK; int lKK; };
struct WPack { WDesc w[4]; };
__global__ __launch_bounds__(256) void cvt_wtrans(CPack pk, WPack wp)
{
    __shared__ float tile[512 * 17];
    int bid = blockIdx.x;
    if (bid < 17296) {
        int idx = 0;
#pragma unroll
        for (int i = 0; i < 8; ++i) idx += (bid >= pk.bound[i]);
        const int base = idx ? pk.bound[idx - 1] : 0;
        const int i = (bid - base) * 256 + threadIdx.x;
        const float4 a = ((const float4*)pk.c[idx].s)[i * 2];
        const float4 b = ((const float4*)pk.c[idx].s)[i * 2 + 1];
        ((s16x8*)pk.c[idx].d)[i] = pack8(a, b);
        return;
    }
    bid -= 17296;
    const WDesc d = wp.w[bid >> 9];
    const int c = bid & 511;
    const int KK = d.KK, lKK = d.lKK;
    const int K = KK << 9;
    const float* src = d.s + (size_t)c * K;
    ushort_t* dst = d.d + (size_t)c * K;
    for (int i = threadIdx.x; i < K; i += 256) {
        int ci = i >> lKK, p = i & (KK - 1);
        tile[ci * (KK + 1) + p] = src[i];
    }
    __syncthreads();
    for (int i = threadIdx.x; i < K; i += 256) {
        int p = i >> 9, ci = i & 511;
        dst[i] = f2bf(tile[ci * (KK + 1) + p]);
    }
}

// ---------------------------------------------------------------------------
// Conv-patch GEMM (MFMA bf16, A bf16 image): C = gather(A)(M,K) * B(512,K)^T
// 128x128 tile, BK=64, global_load_lds(16B) staging.
// T3+T4: double-buffered LDS with COUNTED-vmcnt barriers (ROUND-14 VERIFIED
// ARTIFACT: best total 419.9us). stage(t+1) issued before compute(t);
// barrier #1 waits only vmcnt(8); raw s_barrier (no full drain). Epilogue
// drains vmcnt(0). sched_barrier(0) pins frag reads (rule #18).
// [round-10 retile 128x64 REGRESSED: occupancy not binding.]
// [round-18 asym depth-2 A REGRESSED: gather latency not the residual stall;
//  2-barrier structure is at its ceiling ~82-95us (session-noise band).]
// [round-19 setprio on attn: null-to-negative; reverted.]
// XOR swizzle on the SOURCE address; fragment reads use matching swizzle.
// 4 jobs merged, 256 blocks each (uniform 32 K-iters/block):
//   conv1-K, conv1-V (M=2048, K=8192, split-K z=4)
//   conv2-K, conv2-V (M=8192, K=2048, z=1)
// Within a job: xcd=loc&7, j=loc>>3, nt=j&3, mz=(j>>2)*8+xcd,
// mt=mz&(2^lMT-1), z=mz>>lMT. klen fixed at 2048 (kstart = z<<11).
// fp32 partials at C + z*M*512 (bias/reduction fused into LN).
// ---------------------------------------------------------------------------
struct GDesc { const ushort_t* A; const ushort_t* B; float* C;
               int M; int K; int lOW; int ls; int lMT; };
struct GPack { GDesc g[4]; };
__global__ __launch_bounds__(256) void conv_gemm(GPack pk)
{
    // double buffer: buf b at lds + b*16384 shorts; within buf: A [0,8192), B [8192,16384)
    __shared__ short lds[32768];

    const int tid = threadIdx.x;
    const int bid = blockIdx.x;
    const GDesc gd = pk.g[bid >> 8];
    const ushort_t* Ap = gd.A;
    const ushort_t* Bp = gd.B;
    float* Cp = gd.C;
    const int M = gd.M, K = gd.K, lOW = gd.lOW, ls = gd.ls, lMT = gd.lMT;

    const int loc = bid & 255;
    const int xcd = loc & 7;
    const int j = loc >> 3;
    const int nt = j & 3;
    const int mz = (j >> 2) * 8 + xcd;
    const int mt = mz & ((1 << lMT) - 1);
    const int z = mz >> lMT;
    const int m0 = mt * 128, n0 = nt * 128;
    const int kstart = z << 11;   // klen = 2048

    const int lane = tid & 63, wave = tid >> 6;
    const int l16 = lane & 15, quad = lane >> 4;
    const int wm = (wave >> 1) * 64;
    const int wn = (wave & 1) * 64;

    // staging maps: slot g covers LDS 16B-block g; content row g>>3,
    // k-block (g&7)^(row&7) (source-side swizzle)
    unsigned abase[4]; int acb[4];
    const ushort_t* bptr[4];
    short* ldsA[4]; short* ldsB[4];
    const int OW = 1 << lOW;
#pragma unroll
    for (int i = 0; i < 4; ++i) {
        const int g = i * 256 + tid;
        const int r = g >> 3, c = g & 7;
        acb[i] = ((c ^ (r & 7)) << 3);
        const int m = m0 + r;
        const int bidx = m >> (2 * lOW);
        const int pix = m & (OW * OW - 1);
        const int oy = pix >> lOW, ox = pix & (OW - 1);
        abase[i] = (unsigned)(bidx * NTOK + (oy << ls) * 64 + (ox << ls)) << 9;
        bptr[i] = Bp + (unsigned)(n0 + r) * K + kstart + acb[i];
        ldsA[i] = lds + (i * 256 + wave * 64) * 8;
        ldsB[i] = lds + 8192 + (i * 256 + wave * 64) * 8;
    }

    f32x4 acc[4][4];
#pragma unroll
    for (int a = 0; a < 4; ++a)
#pragma unroll
        for (int b = 0; b < 4; ++b)
            acc[a][b] = (f32x4){0.f, 0.f, 0.f, 0.f};

    const int lsm = (1 << ls) - 1;

    // stage tile t into buffer b (8 x 16B DMA per thread)
    auto stage = [&](int t, int b) {
        const int k0 = kstart + (t << 6);
        const int boff = b << 14;   // 16384 shorts
#pragma unroll
        for (int i = 0; i < 4; ++i) {
            const int k = k0 + acb[i];
            const int p = k >> 9;
            const int ky = p >> ls, kx = p & lsm;
            gld16(Ap + abase[i] + ((unsigned)(ky * 64 + kx) << 9) + (k & 511),
                  ldsA[i] + boff);
            gld16(bptr[i] + (t << 6), ldsB[i] + boff);
        }
    };

    stage(0, 0);   // 8 DMAs in flight
#pragma unroll 1
    for (int t = 0; t < 32; ++t) {
        if (t + 1 < 32) {
            stage(t + 1, (t + 1) & 1);   // +8 DMAs -> 16 in flight
            // wait only for stage(t)'s 8 (oldest); stage(t+1)'s fly on
            asm volatile("s_waitcnt vmcnt(8)" ::: "memory");
        } else {
            asm volatile("s_waitcnt vmcnt(0)" ::: "memory");
        }
        __builtin_amdgcn_sched_barrier(0);   // no frag reads above this point
        __builtin_amdgcn_s_barrier();        // stage(t) visible to all waves

        const short* Abuf = lds + ((t & 1) << 14);
        const short* Bbuf = Abuf + 8192;
#pragma unroll
        for (int kk = 0; kk < 2; ++kk) {
            const int sw = ((quad + kk * 4) ^ (l16 & 7)) << 3;
            s16x8 af[4], bfv[4];
#pragma unroll
            for (int f = 0; f < 4; ++f)
                af[f] = *(const s16x8*)&Abuf[(wm + f * 16 + l16) * 64 + sw];
#pragma unroll
            for (int f = 0; f < 4; ++f)
                bfv[f] = *(const s16x8*)&Bbuf[(wn + f * 16 + l16) * 64 + sw];
#pragma unroll
            for (int a = 0; a < 4; ++a)
#pragma unroll
                for (int b = 0; b < 4; ++b)
                    acc[a][b] = __builtin_amdgcn_mfma_f32_16x16x32_bf16(
                        af[a], bfv[b], acc[a][b], 0, 0, 0);
        }
        __builtin_amdgcn_sched_barrier(0);   // all frag reads of buf t above
        __builtin_amdgcn_s_barrier();        // before t+1 issues stage(t+2) into buf t
        asm volatile("" ::: "memory");
    }

    float* __restrict__ Cz = Cp + (size_t)z * M * 512;
#pragma unroll
    for (int a = 0; a < 4; ++a) {
        const int m = m0 + wm + a * 16 + quad * 4;
#pragma unroll
        for (int b = 0; b < 4; ++b) {
            const int n = n0 + wn + b * 16 + l16;
#pragma unroll
            for (int r = 0; r < 4; ++r)
                Cz[(unsigned)(m + r) * 512 + n] = acc[a][b][r];
        }
    }
}

// ---------------------------------------------------------------------------
// 64x64-tile, K=512 GEMM body (bf16 in; OBF 1: bf16 out, 0: fp32 out + bias)
// ---------------------------------------------------------------------------
template <int OBF>
__device__ __forceinline__ void gemm64_k512(
    short* lds, const ushort_t* __restrict__ Ab, const ushort_t* __restrict__ Bp,
    const float* __restrict__ bias, void* __restrict__ Cp_,
    int m0, int n0, int N, float oscale)
{
    const int tid = threadIdx.x;
    const int lane = tid & 63, wave = tid >> 6;
    const int l16 = lane & 15, quad = lane >> 4;
    const int wm = (wave >> 1) * 32;
    const int wn = (wave & 1) * 32;

    auto off = [](int r, int c) -> int {
        return ((r >> 1) << 6) + (((((r & 1) << 2) | c) ^ ((r >> 1) & 7)) << 3);
    };

    const int cs = (tid & 3) * 8;
    const int ofA = off(tid >> 2, tid & 3);
    const unsigned ab = (unsigned)(m0 + (tid >> 2)) * 512;
    const unsigned bb = (unsigned)(n0 + (tid >> 2)) * 512;

    s16x8 aR, bR;
    auto loadg = [&](int t) {
        aR = *(const s16x8*)(Ab + ab + t * 32 + cs);
        bR = *(const s16x8*)(Bp + bb + t * 32 + cs);
    };
    auto stg = [&](int buf) {
        short* A = lds + buf * 4096;
        short* Bs = A + 2048;
        *(s16x8*)&A[ofA] = aR;
        *(s16x8*)&Bs[ofA] = bR;
    };

    f32x4 acc[2][2];
#pragma unroll
    for (int a = 0; a < 2; ++a)
#pragma unroll
        for (int b = 0; b < 2; ++b)
            acc[a][b] = (f32x4){0.f, 0.f, 0.f, 0.f};

    loadg(0); stg(0); __syncthreads();
#pragma unroll 1
    for (int t = 0; t < 16; ++t) {
        if (t + 1 < 16) loadg(t + 1);
        const short* A = lds + (t & 1) * 4096;
        const short* Bs = A + 2048;
        s16x8 af[2], bfv[2];
#pragma unroll
        for (int f = 0; f < 2; ++f)
            af[f] = *(const s16x8*)&A[off(wm + f * 16 + l16, quad)];
#pragma unroll
        for (int f = 0; f < 2; ++f)
            bfv[f] = *(const s16x8*)&Bs[off(wn + f * 16 + l16, quad)];
#pragma unroll
        for (int a = 0; a < 2; ++a)
#pragma unroll
            for (int b = 0; b < 2; ++b)
                acc[a][b] = __builtin_amdgcn_mfma_f32_16x16x32_bf16(
                    af[a], bfv[b], acc[a][b], 0, 0, 0);
        if (t + 1 < 16) { stg((t + 1) & 1); __syncthreads(); }
    }

#pragma unroll
    for (int a = 0; a < 2; ++a) {
        const int m = m0 + wm + a * 16 + quad * 4;
#pragma unroll
        for (int b = 0; b < 2; ++b) {
            const int n = n0 + wn + b * 16 + l16;
            const float bv = bias ? bias[n] : 0.f;
#pragma unroll
            for (int r = 0; r < 4; ++r) {
                const float val = acc[a][b][r] * oscale + bv;
                if constexpr (OBF)
                    ((ushort_t*)Cp_)[(unsigned)(m + r) * N + n] = f2bf(val);
                else
                    ((float*)Cp_)[(unsigned)(m + r) * N + n] = val;
            }
        }
    }
}

// Merged q/k1/v1/k2/v2 projections (one launch, 1480 blocks)
struct PDesc { const ushort_t* A; const ushort_t* B; ushort_t* C; int lnT; float scale; };
struct PPack { PDesc d[5]; int bound[5]; };
__global__ __launch_bounds__(256) void proj_gemm(PPack pk)
{
    __shared__ short lds[8192];
    const int bid = blockIdx.x;
    int idx = 0;
#pragma unroll
    for (int i = 0; i < 4; ++i) idx += (bid >= pk.bound[i]);
    const PDesc d = pk.d[idx];
    const int base = idx ? pk.bound[idx - 1] : 0;
    const int loc = bid - base;
    const int nt = loc & ((1 << d.lnT) - 1);
    const int mt = loc >> d.lnT;
    gemm64_k512<1>(lds, d.A, d.B, nullptr, d.C, mt * 64, nt * 64, 64 << d.lnT, d.scale);
}

// Final projection: fp32 out + bias, 200 blocks
__global__ __launch_bounds__(256) void final_gemm(
    const ushort_t* __restrict__ A, const ushort_t* __restrict__ B,
    const float* __restrict__ bias, float* __restrict__ C)
{
    __shared__ short lds[8192];
    const int m0 = (blockIdx.x >> 3) * 64;
    const int n0 = (blockIdx.x & 7) * 64;
    gemm64_k512<0>(lds, A, B, bias, C, m0, n0, 512, 1.0f);
}

// ---------------------------------------------------------------------------
// LayerNorm + ReLU6 with fused split-K reduction + conv bias; all 4 jobs
// (key1, val1, key2, val2) in one launch. dst bf16.
// ---------------------------------------------------------------------------
struct LDesc { ushort_t* d; const float* s; const float* cb;
               const float* g; const float* b; unsigned pstride; int np; };
struct LPack { LDesc l[4]; int bound[4]; };
__global__ __launch_bounds__(256) void ln_all(LPack pk)
{
    const int bid = blockIdx.x;
    int idx = 0;
#pragma unroll
    for (int i = 0; i < 3; ++i) idx += (bid >= pk.bound[i]);
    const LDesc d = pk.l[idx];
    const int base = idx ? pk.bound[idx - 1] : 0;
    const int blk = bid - base;
    const int row = blk * 4 + (threadIdx.x >> 6);
    const int lane = threadIdx.x & 63;
    float v[8];
#pragma unroll
    for (int j = 0; j < 8; ++j) v[j] = d.cb[lane + 64 * j];
    const float* p = d.s + (size_t)row * DIM;
    for (int ip = 0; ip < d.np; ++ip) {
#pragma unroll
        for (int j = 0; j < 8; ++j) v[j] += p[lane + 64 * j];
        p += d.pstride;
    }
    float s1v = 0.f, s2v = 0.f;
#pragma unroll
    for (int j = 0; j < 8; ++j) { s1v += v[j]; s2v += v[j] * v[j]; }
#pragma unroll
    for (int off = 32; off; off >>= 1) {
        s1v += __shfl_xor(s1v, off, 64);
        s2v += __shfl_xor(s2v, off, 64);
    }
    const float mean = s1v * (1.0f / DIM);
    const float var = s2v * (1.0f / DIM) - mean * mean;
    const float rstd = rsqrtf(var + 1e-5f);
    ushort_t* q = d.d + (size_t)row * DIM;
#pragma unroll
    for (int j = 0; j < 8; ++j) {
        const int c = lane + 64 * j;
        float y = (v[j] - mean) * rstd * d.g[c] + d.b[c];
        q[c] = f2bf(fminf(fmaxf(y, 0.0f), 6.0f));
    }
}

// ---------------------------------------------------------------------------
// vplus = v + dwconv3x3 + bias, both branches in one launch
// ---------------------------------------------------------------------------
__device__ __forceinline__ void vplus_body(
    const ushort_t* __restrict__ vbuf, const float* __restrict__ lw,
    const float* __restrict__ lb, ushort_t* __restrict__ out,
    int lOW, int lL, int blk)
{
    const int idx = blk * 256 + threadIdx.x;
    const int c = idx & 255;
    const int pix = (idx >> 8) & ((1 << lL) - 1);
    const int b = idx >> (8 + lL);
    const int OW = 1 << lOW;
    const int y = pix >> lOW, x = pix & (OW - 1);
    float acc = lb[c];
#pragma unroll
    for (int dy = -1; dy <= 1; ++dy) {
        const int ny = y + dy;
        if ((unsigned)ny >= (unsigned)OW) continue;
#pragma unroll
        for (int dx = -1; dx <= 1; ++dx) {
            const int nx = x + dx;
            if ((unsigned)nx >= (unsigned)OW) continue;
            acc += bf2f(vbuf[(((unsigned)(b << lL) + ny * OW + nx) << 8) + c]) *
                   lw[c * 9 + (dy + 1) * 3 + (dx + 1)];
        }
    }
    out[idx] = f2bf(bf2f(vbuf[idx]) + acc);
}

__global__ __launch_bounds__(256) void vplus2_kernel(
    const ushort_t* v1, const float* w1, const float* b1, ushort_t* o1,
    const ushort_t* v2, const float* w2, const float* b2, ushort_t* o2)
{
    const int bid = blockIdx.x;
    if (bid < 2048) vplus_body(v1, w1, b1, o1, 4, 8, bid);
    else            vplus_body(v2, w2, b2, o2, 5, 10, bid - 2048);
}

// ---------------------------------------------------------------------------
// MFMA attention, all operands bf16 (Q pre-scaled by 0.125 in q-projection).
// Both branches merged into one launch: grid z in [0,8) = branch1 (L=256),
// [8,16) = branch2 (L=1024). Static 77,888B LDS (2 blocks/CU).
// WAVE-PRIVATE K/V staging (round-12, verified): phases A and C barrier-free
// via same-wave DS ordering. [round-19 setprio: null-to-negative; reverted.]
// ---------------------------------------------------------------------------
template <int L>
__device__ __forceinline__ void attn_body(
    char* smem,
    const ushort_t* __restrict__ qbuf, const ushort_t* __restrict__ kbuf,
    const ushort_t* __restrict__ vbuf, ushort_t* __restrict__ xbuf,
    const int hoff, const int coff, const int b)
{
    constexpr int SP = L + 12;
    constexpr int NV = L / 64;
    float (*S)[SP]   = (float (*)[SP])smem;                       // 16*SP*4 B
    float* invs      = (float*)(smem + 64 * SP);                  // 64 B
    short (*Qs)[72]  = (short (*)[72])(smem + 64 * SP + 64);      // 2304 B
    short (*KV)[72]  = (short (*)[72])(smem + 64 * SP + 64 + 2304); // 9216 B

    const int tid = threadIdx.x;
    const int qt = blockIdx.x;
    const int h = blockIdx.y;
    const int lane = tid & 63, wave = tid >> 6;
    const int l16 = lane & 15, quad = lane >> 4;

    {
        const int r = tid >> 4, d0 = (tid & 15) * 4;
        int qi = qt * 16 + r; if (qi > QN - 1) qi = QN - 1;
        *(s16x4*)&Qs[r][d0] = *(const s16x4*)(
            qbuf + ((unsigned)(b * QN + qi) * NHEAD + hoff + h) * HD + d0);
    }
    __syncthreads();   // publish Qs (phase A itself needs no barriers)

    // Q fragments are loop-invariant: hoist once.
    s16x8 qf[2];
#pragma unroll
    for (int c = 0; c < 2; ++c)
        qf[c] = *(const s16x8*)&Qs[l16][c * 32 + quad * 8];

    // ---- Phase A: S = Q K^T ---- (KV rows wave-private; no barriers)
    const int klr = tid >> 2, kd0 = (tid & 3) * 16;
    for (int l0 = 0; l0 < L; l0 += 64) {
        const unsigned src = (unsigned)(b * L + l0 + klr) * C2 + h * HD + kd0;
        const s16x8 x0 = *(const s16x8*)(kbuf + src);
        const s16x8 x1 = *(const s16x8*)(kbuf + src + 8);
        *(s16x8*)&KV[klr][kd0] = x0;
        *(s16x8*)&KV[klr][kd0 + 8] = x1;
        f32x4 sacc = (f32x4){0.f, 0.f, 0.f, 0.f};
#pragma unroll
        for (int c = 0; c < 2; ++c) {
            const s16x8 bf = *(const s16x8*)&KV[wave * 16 + l16][c * 32 + quad * 8];
            sacc = __builtin_amdgcn_mfma_f32_16x16x32_bf16(qf[c], bf, sacc, 0, 0, 0);
        }
        const int col = l0 + wave * 16 + l16;
#pragma unroll
        for (int r = 0; r < 4; ++r) S[quad * 4 + r][col] = sacc[r];
    }
    __syncthreads();   // publish S for softmax

    // ---- Phase B: softmax ---- (rows wave-private)
#pragma unroll
    for (int rr = 0; rr < 4; ++rr) {
        const int row = wave * 4 + rr;
        float v[NV];
#pragma unroll
        for (int k = 0; k < NV; ++k) v[k] = S[row][lane + 64 * k];
        float m = -1e30f;
#pragma unroll
        for (int k = 0; k < NV; ++k) m = fmaxf(m, v[k]);
#pragma unroll
        for (int off = 32; off; off >>= 1) m = fmaxf(m, __shfl_xor(m, off, 64));
        float s = 0.f;
#pragma unroll
        for (int k = 0; k < NV; ++k) {
            v[k] = __expf(v[k] - m);
            s += v[k];
        }
#pragma unroll
        for (int off = 32; off; off >>= 1) s += __shfl_xor(s, off, 64);
#pragma unroll
        for (int k = 0; k < NV; ++k) S[row][lane + 64 * k] = v[k];
        if (lane == 0) invs[row] = 1.0f / s;
    }
    __syncthreads();   // publish softmax'd S + invs before PV

    // ---- Phase C: O = P V ---- (KV channel rows wave-private; no barriers)
    f32x4 oacc = (f32x4){0.f, 0.f, 0.f, 0.f};
    const int ctok = lane >> 2;                   // 0..15
    const int cd0 = wave * 16 + (lane & 3) * 4;   // wave-private channel base
    for (int l0 = 0; l0 < L; l0 += 64) {
#pragma unroll
        for (int p = 0; p < 4; ++p) {
            const int token = p * 16 + ctok;
            const s16x4 v = *(const s16x4*)(
                vbuf + (unsigned)(b * L + l0 + token) * C2 + h * HD + cd0);
            KV[cd0 + 0][token] = v[0];
            KV[cd0 + 1][token] = v[1];
            KV[cd0 + 2][token] = v[2];
            KV[cd0 + 3][token] = v[3];
        }
#pragma unroll
        for (int c = 0; c < 2; ++c) {
            const float4 p0 = *(const float4*)&S[l16][l0 + c * 32 + quad * 8];
            const float4 p1 = *(const float4*)&S[l16][l0 + c * 32 + quad * 8 + 4];
            const s16x8 af = pack8(p0, p1);
            const s16x8 bf = *(const s16x8*)&KV[wave * 16 + l16][c * 32 + quad * 8];
            oacc = __builtin_amdgcn_mfma_f32_16x16x32_bf16(af, bf, oacc, 0, 0, 0);
        }
    }

    const int dcol = wave * 16 + l16;
#pragma unroll
    for (int r = 0; r < 4; ++r) {
        const int q = quad * 4 + r;
        const int qi = qt * 16 + q;
        if (qi < QN) {
            const float val = oacc[r] * invs[q];
            const int flat = ((b * QN + qi) * NH2 + h) * HD + dcol;
            xbuf[(unsigned)(flat >> 8) * DIM + coff + (flat & 255)] = f2bf(val);
        }
    }
}

__global__ __launch_bounds__(256) void attn_both(
    const ushort_t* __restrict__ qbuf,
    const ushort_t* __restrict__ k1, const ushort_t* __restrict__ vp1,
    const ushort_t* __restrict__ k2, const ushort_t* __restrict__ vp2,
    ushort_t* __restrict__ xbuf)
{
    __shared__ char smem[77888] __attribute__((aligned(16)));
    const int bz = blockIdx.z;
    if (bz < 8) attn_body<256>(smem, qbuf, k1, vp1, xbuf, 0, 0, bz);
    else        attn_body<1024>(smem, qbuf, k2, vp2, xbuf, 4, 256, bz - 8);
}

// ---------------------------------------------------------------------------
// Launcher
// ---------------------------------------------------------------------------
extern "C" void kernel_launch(void* const* d_in, const int* in_sizes, int n_in,
                              void* d_out, int out_size, void* d_ws, size_t ws_size,
                              hipStream_t stream)
{
    const float* query   = (const float*)d_in[0];
    const float* key     = (const float*)d_in[1];
    const float* value   = (const float*)d_in[2];
    const float* q_w     = (const float*)d_in[3];
    const float* sr1_1_w = (const float*)d_in[4];
    const float* sr1_1_b = (const float*)d_in[5];
    const float* n1_1_g  = (const float*)d_in[6];
    const float* n1_1_b  = (const float*)d_in[7];
    const float* sr1_2_w = (const float*)d_in[8];
    const float* sr1_2_b = (const float*)d_in[9];
    const float* n1_2_g  = (const float*)d_in[10];
    const float* n1_2_b  = (const float*)d_in[11];
    const float* sr2_1_w = (const float*)d_in[12];
    const float* sr2_1_b = (const float*)d_in[13];
    const float* n2_1_g  = (const float*)d_in[14];
    const float* n2_1_b  = (const float*)d_in[15];
    const float* sr2_2_w = (const float*)d_in[16];
    const float* sr2_2_b = (const float*)d_in[17];
    const float* n2_2_g  = (const float*)d_in[18];
    const float* n2_2_b  = (const float*)d_in[19];
    const float* k1_w    = (const float*)d_in[20];
    const float* v1_w    = (const float*)d_in[21];
    const float* k2_w    = (const float*)d_in[22];
    const float* v2_w    = (const float*)d_in[23];
    const float* lc1_w   = (const float*)d_in[24];
    const float* lc1_b   = (const float*)d_in[25];
    const float* lc2_w   = (const float*)d_in[26];
    const float* lc2_b   = (const float*)d_in[27];
    const float* proj_w  = (const float*)d_in[28];
    const float* proj_b  = (const float*)d_in[29];
    float* out = (float*)d_out;
    char* ws = (char*)d_ws;

    // --- workspace layout (bytes); total ~199 MB (d_ws is 256 MiB) ---
    ushort_t* IMGK  = (ushort_t*)(ws + 0);            // 33.5 MB
    ushort_t* IMGV  = (ushort_t*)(ws + 33554432);     // 33.5 MB
    float*    SCRK1 = (float*)(ws + 67108864);        // 16.8 MB fp32 partials
    float*    SCRV1 = (float*)(ws + 83886080);        // 16.8 MB
    float*    SCRK2 = (float*)(ws + 100663296);       // 16.8 MB
    float*    SCRV2 = (float*)(ws + 117440512);       // 16.8 MB
    ushort_t* WT1K  = (ushort_t*)(ws + 134217728);    // 8.4 MB
    ushort_t* WT1V  = (ushort_t*)(ws + 142606336);    // 8.4 MB
    ushort_t* WT2K  = (ushort_t*)(ws + 150994944);    // 2.1 MB
    ushort_t* WT2V  = (ushort_t*)(ws + 153092096);    // 2.1 MB
    ushort_t* KEY1  = (ushort_t*)(ws + 155189248);    // 2.1 MB
    ushort_t* VAL1  = (ushort_t*)(ws + 157286400);
    ushort_t* KEY2  = (ushort_t*)(ws + 159383552);    // 8.4 MB
    ushort_t* VAL2  = (ushort_t*)(ws + 167772160);
    ushort_t* QRYB  = (ushort_t*)(ws + 176160768);    // 1600x512 bf16
    ushort_t* WQ    = (ushort_t*)(ws + 177799168);
    ushort_t* WK1   = (ushort_t*)(ws + 178323456);
    ushort_t* WV1   = (ushort_t*)(ws + 178585600);
    ushort_t* WK2   = (ushort_t*)(ws + 178847744);
    ushort_t* WV2   = (ushort_t*)(ws + 179109888);
    ushort_t* WP    = (ushort_t*)(ws + 179372032);
    ushort_t* QBUF  = (ushort_t*)(ws + 179896320);
    ushort_t* XBUF  = (ushort_t*)(ws + 181534720);
    ushort_t* K1    = (ushort_t*)(ws + 183173120);
    ushort_t* V1    = (ushort_t*)(ws + 184221696);
    ushort_t* VP1   = (ushort_t*)(ws + 185270272);
    ushort_t* K2    = (ushort_t*)(ws + 186318848);
    ushort_t* V2    = (ushort_t*)(ws + 190513152);
    ushort_t* VP2   = (ushort_t*)(ws + 194707456);    // ends 198,901,760

    // 1) all fp32->bf16 conversions + conv-weight transposes (one launch)
    CPack cp;
    cp.c[0] = {key,   IMGK}; cp.c[1] = {value, IMGV}; cp.c[2] = {query, QRYB};
    cp.c[3] = {q_w,   WQ};   cp.c[4] = {k1_w,  WK1};  cp.c[5] = {v1_w,  WV1};
    cp.c[6] = {k2_w,  WK2};  cp.c[7] = {v2_w,  WV2};  cp.c[8] = {proj_w, WP};
    cp.bound[0] = 8192;  cp.bound[1] = 16384; cp.bound[2] = 16784;
    cp.bound[3] = 16912; cp.bound[4] = 16976; cp.bound[5] = 17040;
    cp.bound[6] = 17104; cp.bound[7] = 17168; cp.bound[8] = 17296;
    WPack wp;
    wp.w[0] = {sr1_1_w, WT1K, 16, 4}; wp.w[1] = {sr1_2_w, WT1V, 16, 4};
    wp.w[2] = {sr2_1_w, WT2K, 4, 2};  wp.w[3] = {sr2_2_w, WT2V, 4, 2};
    cvt_wtrans<<<19344, 256, 0, stream>>>(cp, wp);

    // 2) all 4 conv GEMMs in one launch, uniform 256 blocks / 32 K-iters each
    //    conv1: split-K z=4 (klen=2048); conv2: z=1
    GPack gp;
    gp.g[0] = {IMGK, WT1K, SCRK1, 2048, 8192, 4, 2, 4};
    gp.g[1] = {IMGV, WT1V, SCRV1, 2048, 8192, 4, 2, 4};
    gp.g[2] = {IMGK, WT2K, SCRK2, 8192, 2048, 5, 1, 6};
    gp.g[3] = {IMGV, WT2V, SCRV2, 8192, 2048, 5, 1, 6};
    conv_gemm<<<1024, 256, 0, stream>>>(gp);

    // 3) all 4 LN+ReLU6 (+split-K reduce + conv bias) in one launch
    LPack lp;
    lp.l[0] = {KEY1, SCRK1, sr1_1_b, n1_1_g, n1_1_b, 1048576u, 4};
    lp.l[1] = {VAL1, SCRV1, sr1_2_b, n1_2_g, n1_2_b, 1048576u, 4};
    lp.l[2] = {KEY2, SCRK2, sr2_1_b, n2_1_g, n2_1_b, 4194304u, 1};
    lp.l[3] = {VAL2, SCRV2, sr2_2_b, n2_2_g, n2_2_b, 4194304u, 1};
    lp.bound[0] = 512; lp.bound[1] = 1024; lp.bound[2] = 3072; lp.bound[3] = 5120;
    ln_all<<<5120, 256, 0, stream>>>(lp);

    // 4) merged projections: q (scale 0.125 folded), k1, v1, k2, v2
    PPack pp;
    pp.d[0] = {QRYB, WQ,  QBUF, 3, 0.125f};
    pp.d[1] = {KEY1, WK1, K1,   2, 1.0f};
    pp.d[2] = {VAL1, WV1, V1,   2, 1.0f};
    pp.d[3] = {KEY2, WK2, K2,   2, 1.0f};
    pp.d[4] = {VAL2, WV2, V2,   2, 1.0f};
    pp.bound[0] = 200; pp.bound[1] = 328; pp.bound[2] = 456; pp.bound[3] = 968;
    pp.bound[4] = 1480;
    proj_gemm<<<1480, 256, 0, stream>>>(pp);

    // 5) v + local dwconv (both branches)
    vplus2_kernel<<<10240, 256, 0, stream>>>(V1, lc1_w, lc1_b, VP1,
                                             V2, lc2_w, lc2_b, VP2);

    // 6) attention, both branches in one launch (co-resident)
    attn_both<<<dim3(13, 4, 16), 256, 0, stream>>>(QBUF, K1, VP1, K2, VP2, XBUF);

    // 7) final projection + bias -> fp32 out
    final_gemm<<<200, 256, 0, stream>>>(XBUF, WP, proj_b, out);
}

// Round 22
// 415.759 us; speedup vs baseline: 1.0294x; 1.0102x over previous
//
#include <hip/hip_runtime.h>
#include <cstddef>
#include <cstdint>

// Problem constants
#define QN   200
#define DIM  512
#define NHEAD 8
#define HD   64
#define C2   256
#define NH2  4
#define NTOK 4096   // 64*64

typedef unsigned short ushort_t;
typedef unsigned int u32;
typedef short s16x4 __attribute__((ext_vector_type(4)));
typedef short s16x8 __attribute__((ext_vector_type(8)));   // 8 bf16 (4 VGPRs)
typedef float f32x4 __attribute__((ext_vector_type(4)));   // MFMA accumulator

__device__ __forceinline__ unsigned short f2bf(float f) {
    unsigned int u = __float_as_uint(f);
    u += 0x7fffu + ((u >> 16) & 1u);   // round-to-nearest-even
    return (unsigned short)(u >> 16);
}
__device__ __forceinline__ float bf2f(unsigned short u) {
    return __uint_as_float(((unsigned int)u) << 16);
}
__device__ __forceinline__ s16x8 pack8(float4 x, float4 y) {
    s16x8 v;
    v[0] = (short)f2bf(x.x); v[1] = (short)f2bf(x.y);
    v[2] = (short)f2bf(x.z); v[3] = (short)f2bf(x.w);
    v[4] = (short)f2bf(y.x); v[5] = (short)f2bf(y.y);
    v[6] = (short)f2bf(y.z); v[7] = (short)f2bf(y.w);
    return v;
}

// global -> LDS 16B DMA (wave-uniform LDS base + lane*16)
__device__ __forceinline__ void gld16(const ushort_t* g, short* l) {
    __builtin_amdgcn_global_load_lds(
        (const __attribute__((address_space(1))) u32*)g,
        (__attribute__((address_space(3))) u32*)l, 16, 0, 0);
}

// ---------------------------------------------------------------------------
// Merged: all fp32->bf16 conversions (9 jobs, blocks [0,17296)) +
// all 4 conv-weight transposes (blocks [17296,19344)).
// wtrans: w (512, 512, KK) fp32 -> wt (512, KK*512) bf16, k'=p*512+ci
// ---------------------------------------------------------------------------
struct CDesc { const float* s; ushort_t* d; };
struct CPack { CDesc c[9]; int bound[9]; };
struct WDesc { const float* s; ushort_t* d; int KK; int lKK; };
struct WPack { WDesc w[4]; };
__global__ __launch_bounds__(256) void cvt_wtrans(CPack pk, WPack wp)
{
    __shared__ float tile[512 * 17];
    int bid = blockIdx.x;
    if (bid < 17296) {
        int idx = 0;
#pragma unroll
        for (int i = 0; i < 8; ++i) idx += (bid >= pk.bound[i]);
        const int base = idx ? pk.bound[idx - 1] : 0;
        const int i = (bid - base) * 256 + threadIdx.x;
        const float4 a = ((const float4*)pk.c[idx].s)[i * 2];
        const float4 b = ((const float4*)pk.c[idx].s)[i * 2 + 1];
        ((s16x8*)pk.c[idx].d)[i] = pack8(a, b);
        return;
    }
    bid -= 17296;
    const WDesc d = wp.w[bid >> 9];
    const int c = bid & 511;
    const int KK = d.KK, lKK = d.lKK;
    const int K = KK << 9;
    const float* src = d.s + (size_t)c * K;
    ushort_t* dst = d.d + (size_t)c * K;
    for (int i = threadIdx.x; i < K; i += 256) {
        int ci = i >> lKK, p = i & (KK - 1);
        tile[ci * (KK + 1) + p] = src[i];
    }
    __syncthreads();
    for (int i = threadIdx.x; i < K; i += 256) {
        int p = i >> 9, ci = i & 511;
        dst[i] = f2bf(tile[ci * (KK + 1) + p]);
    }
}

// ---------------------------------------------------------------------------
// Conv-patch GEMM (MFMA bf16, A bf16 image): C = gather(A)(M,K) * B(512,K)^T
// 128x128 tile, BK=64, global_load_lds(16B) staging.
// T3+T4: double-buffered LDS with COUNTED-vmcnt barriers (round-14 verified
// structure; best total 419.9us). stage(t+1) issued before compute(t);
// barrier #1 waits only vmcnt(8); raw s_barrier (no full drain). Epilogue
// drains vmcnt(0). sched_barrier(0) pins frag reads (rule #18).
// [round-10 retile 128x64 REGRESSED; round-18 asym depth REGRESSED;
//  round-19 setprio REGRESSED. 2-barrier structure is the keeper.]
// ROUND-20 param change: conv1 split-K z=4 -> 2 (klen=4096, nk=64/block,
// 128 blocks/job) halves fp32 partial round-trip; conv2 unchanged.
// Jobs have different block counts -> bounds-array job select:
//   conv1-K [0,128), conv1-V [128,256), conv2-K [256,512), conv2-V [512,768)
// Within a job: xcd=loc&7, j=loc>>3, nt=j&3, mz=(j>>2)*8+xcd,
// mt=mz&(2^lMT-1), z=mz>>lMT. kstart = z<<lKL.
// fp32 partials at C + z*M*512 (bias/reduction fused into LN).
// ---------------------------------------------------------------------------
struct GDesc { const ushort_t* A; const ushort_t* B; float* C;
               int M; int K; int lOW; int ls; int lMT; int lKL; int nk; };
struct GPack { GDesc g[4]; int bound[4]; };
__global__ __launch_bounds__(256) void conv_gemm(GPack pk)
{
    // double buffer: buf b at lds + b*16384 shorts; within buf: A [0,8192), B [8192,16384)
    __shared__ short lds[32768];

    const int tid = threadIdx.x;
    const int bid = blockIdx.x;
    int idx = 0;
#pragma unroll
    for (int i = 0; i < 3; ++i) idx += (bid >= pk.bound[i]);
    const GDesc gd = pk.g[idx];
    const int base = idx ? pk.bound[idx - 1] : 0;
    const ushort_t* Ap = gd.A;
    const ushort_t* Bp = gd.B;
    float* Cp = gd.C;
    const int M = gd.M, K = gd.K, lOW = gd.lOW, ls = gd.ls, lMT = gd.lMT;
    const int nk = gd.nk;

    const int loc = bid - base;
    const int xcd = loc & 7;
    const int j = loc >> 3;
    const int nt = j & 3;
    const int mz = (j >> 2) * 8 + xcd;
    const int mt = mz & ((1 << lMT) - 1);
    const int z = mz >> lMT;
    const int m0 = mt * 128, n0 = nt * 128;
    const int kstart = z << gd.lKL;

    const int lane = tid & 63, wave = tid >> 6;
    const int l16 = lane & 15, quad = lane >> 4;
    const int wm = (wave >> 1) * 64;
    const int wn = (wave & 1) * 64;

    // staging maps: slot g covers LDS 16B-block g; content row g>>3,
    // k-block (g&7)^(row&7) (source-side swizzle)
    unsigned abase[4]; int acb[4];
    const ushort_t* bptr[4];
    short* ldsA[4]; short* ldsB[4];
    const int OW = 1 << lOW;
#pragma unroll
    for (int i = 0; i < 4; ++i) {
        const int g = i * 256 + tid;
        const int r = g >> 3, c = g & 7;
        acb[i] = ((c ^ (r & 7)) << 3);
        const int m = m0 + r;
        const int bidx = m >> (2 * lOW);
        const int pix = m & (OW * OW - 1);
        const int oy = pix >> lOW, ox = pix & (OW - 1);
        abase[i] = (unsigned)(bidx * NTOK + (oy << ls) * 64 + (ox << ls)) << 9;
        bptr[i] = Bp + (unsigned)(n0 + r) * K + kstart + acb[i];
        ldsA[i] = lds + (i * 256 + wave * 64) * 8;
        ldsB[i] = lds + 8192 + (i * 256 + wave * 64) * 8;
    }

    f32x4 acc[4][4];
#pragma unroll
    for (int a = 0; a < 4; ++a)
#pragma unroll
        for (int b = 0; b < 4; ++b)
            acc[a][b] = (f32x4){0.f, 0.f, 0.f, 0.f};

    const int lsm = (1 << ls) - 1;

    // stage tile t into buffer b (8 x 16B DMA per thread)
    auto stage = [&](int t, int b) {
        const int k0 = kstart + (t << 6);
        const int boff = b << 14;   // 16384 shorts
#pragma unroll
        for (int i = 0; i < 4; ++i) {
            const int k = k0 + acb[i];
            const int p = k >> 9;
            const int ky = p >> ls, kx = p & lsm;
            gld16(Ap + abase[i] + ((unsigned)(ky * 64 + kx) << 9) + (k & 511),
                  ldsA[i] + boff);
            gld16(bptr[i] + (t << 6), ldsB[i] + boff);
        }
    };

    stage(0, 0);   // 8 DMAs in flight
#pragma unroll 1
    for (int t = 0; t < nk; ++t) {
        if (t + 1 < nk) {
            stage(t + 1, (t + 1) & 1);   // +8 DMAs -> 16 in flight
            // wait only for stage(t)'s 8 (oldest); stage(t+1)'s fly on
            asm volatile("s_waitcnt vmcnt(8)" ::: "memory");
        } else {
            asm volatile("s_waitcnt vmcnt(0)" ::: "memory");
        }
        __builtin_amdgcn_sched_barrier(0);   // no frag reads above this point
        __builtin_amdgcn_s_barrier();        // stage(t) visible to all waves

        const short* Abuf = lds + ((t & 1) << 14);
        const short* Bbuf = Abuf + 8192;
#pragma unroll
        for (int kk = 0; kk < 2; ++kk) {
            const int sw = ((quad + kk * 4) ^ (l16 & 7)) << 3;
            s16x8 af[4], bfv[4];
#pragma unroll
            for (int f = 0; f < 4; ++f)
                af[f] = *(const s16x8*)&Abuf[(wm + f * 16 + l16) * 64 + sw];
#pragma unroll
            for (int f = 0; f < 4; ++f)
                bfv[f] = *(const s16x8*)&Bbuf[(wn + f * 16 + l16) * 64 + sw];
#pragma unroll
            for (int a = 0; a < 4; ++a)
#pragma unroll
                for (int b = 0; b < 4; ++b)
                    acc[a][b] = __builtin_amdgcn_mfma_f32_16x16x32_bf16(
                        af[a], bfv[b], acc[a][b], 0, 0, 0);
        }
        __builtin_amdgcn_sched_barrier(0);   // all frag reads of buf t above
        __builtin_amdgcn_s_barrier();        // before t+1 issues stage(t+2) into buf t
        asm volatile("" ::: "memory");
    }

    float* __restrict__ Cz = Cp + (size_t)z * M * 512;
#pragma unroll
    for (int a = 0; a < 4; ++a) {
        const int m = m0 + wm + a * 16 + quad * 4;
#pragma unroll
        for (int b = 0; b < 4; ++b) {
            const int n = n0 + wn + b * 16 + l16;
#pragma unroll
            for (int r = 0; r < 4; ++r)
                Cz[(unsigned)(m + r) * 512 + n] = acc[a][b][r];
        }
    }
}

// ---------------------------------------------------------------------------
// 64x64-tile, K=512 GEMM body (bf16 in; OBF 1: bf16 out, 0: fp32 out + bias)
// ---------------------------------------------------------------------------
template <int OBF>
__device__ __forceinline__ void gemm64_k512(
    short* lds, const ushort_t* __restrict__ Ab, const ushort_t* __restrict__ Bp,
    const float* __restrict__ bias, void* __restrict__ Cp_,
    int m0, int n0, int N, float oscale)
{
    const int tid = threadIdx.x;
    const int lane = tid & 63, wave = tid >> 6;
    const int l16 = lane & 15, quad = lane >> 4;
    const int wm = (wave >> 1) * 32;
    const int wn = (wave & 1) * 32;

    auto off = [](int r, int c) -> int {
        return ((r >> 1) << 6) + (((((r & 1) << 2) | c) ^ ((r >> 1) & 7)) << 3);
    };

    const int cs = (tid & 3) * 8;
    const int ofA = off(tid >> 2, tid & 3);
    const unsigned ab = (unsigned)(m0 + (tid >> 2)) * 512;
    const unsigned bb = (unsigned)(n0 + (tid >> 2)) * 512;

    s16x8 aR, bR;
    auto loadg = [&](int t) {
        aR = *(const s16x8*)(Ab + ab + t * 32 + cs);
        bR = *(const s16x8*)(Bp + bb + t * 32 + cs);
    };
    auto stg = [&](int buf) {
        short* A = lds + buf * 4096;
        short* Bs = A + 2048;
        *(s16x8*)&A[ofA] = aR;
        *(s16x8*)&Bs[ofA] = bR;
    };

    f32x4 acc[2][2];
#pragma unroll
    for (int a = 0; a < 2; ++a)
#pragma unroll
        for (int b = 0; b < 2; ++b)
            acc[a][b] = (f32x4){0.f, 0.f, 0.f, 0.f};

    loadg(0); stg(0); __syncthreads();
#pragma unroll 1
    for (int t = 0; t < 16; ++t) {
        if (t + 1 < 16) loadg(t + 1);
        const short* A = lds + (t & 1) * 4096;
        const short* Bs = A + 2048;
        s16x8 af[2], bfv[2];
#pragma unroll
        for (int f = 0; f < 2; ++f)
            af[f] = *(const s16x8*)&A[off(wm + f * 16 + l16, quad)];
#pragma unroll
        for (int f = 0; f < 2; ++f)
            bfv[f] = *(const s16x8*)&Bs[off(wn + f * 16 + l16, quad)];
#pragma unroll
        for (int a = 0; a < 2; ++a)
#pragma unroll
            for (int b = 0; b < 2; ++b)
                acc[a][b] = __builtin_amdgcn_mfma_f32_16x16x32_bf16(
                    af[a], bfv[b], acc[a][b], 0, 0, 0);
        if (t + 1 < 16) { stg((t + 1) & 1); __syncthreads(); }
    }

#pragma unroll
    for (int a = 0; a < 2; ++a) {
        const int m = m0 + wm + a * 16 + quad * 4;
#pragma unroll
        for (int b = 0; b < 2; ++b) {
            const int n = n0 + wn + b * 16 + l16;
            const float bv = bias ? bias[n] : 0.f;
#pragma unroll
            for (int r = 0; r < 4; ++r) {
                const float val = acc[a][b][r] * oscale + bv;
                if constexpr (OBF)
                    ((ushort_t*)Cp_)[(unsigned)(m + r) * N + n] = f2bf(val);
                else
                    ((float*)Cp_)[(unsigned)(m + r) * N + n] = val;
            }
        }
    }
}

// Merged q/k1/v1/k2/v2 projections (one launch, 1480 blocks)
struct PDesc { const ushort_t* A; const ushort_t* B; ushort_t* C; int lnT; float scale; };
struct PPack { PDesc d[5]; int bound[5]; };
__global__ __launch_bounds__(256) void proj_gemm(PPack pk)
{
    __shared__ short lds[8192];
    const int bid = blockIdx.x;
    int idx = 0;
#pragma unroll
    for (int i = 0; i < 4; ++i) idx += (bid >= pk.bound[i]);
    const PDesc d = pk.d[idx];
    const int base = idx ? pk.bound[idx - 1] : 0;
    const int loc = bid - base;
    const int nt = loc & ((1 << d.lnT) - 1);
    const int mt = loc >> d.lnT;
    gemm64_k512<1>(lds, d.A, d.B, nullptr, d.C, mt * 64, nt * 64, 64 << d.lnT, d.scale);
}

// Final projection: fp32 out + bias, 200 blocks
__global__ __launch_bounds__(256) void final_gemm(
    const ushort_t* __restrict__ A, const ushort_t* __restrict__ B,
    const float* __restrict__ bias, float* __restrict__ C)
{
    __shared__ short lds[8192];
    const int m0 = (blockIdx.x >> 3) * 64;
    const int n0 = (blockIdx.x & 7) * 64;
    gemm64_k512<0>(lds, A, B, bias, C, m0, n0, 512, 1.0f);
}

// ---------------------------------------------------------------------------
// LayerNorm + ReLU6 with fused split-K reduction + conv bias; all 4 jobs
// (key1, val1, key2, val2) in one launch. dst bf16.
// ---------------------------------------------------------------------------
struct LDesc { ushort_t* d; const float* s; const float* cb;
               const float* g; const float* b; unsigned pstride; int np; };
struct LPack { LDesc l[4]; int bound[4]; };
__global__ __launch_bounds__(256) void ln_all(LPack pk)
{
    const int bid = blockIdx.x;
    int idx = 0;
#pragma unroll
    for (int i = 0; i < 3; ++i) idx += (bid >= pk.bound[i]);
    const LDesc d = pk.l[idx];
    const int base = idx ? pk.bound[idx - 1] : 0;
    const int blk = bid - base;
    const int row = blk * 4 + (threadIdx.x >> 6);
    const int lane = threadIdx.x & 63;
    float v[8];
#pragma unroll
    for (int j = 0; j < 8; ++j) v[j] = d.cb[lane + 64 * j];
    const float* p = d.s + (size_t)row * DIM;
    for (int ip = 0; ip < d.np; ++ip) {
#pragma unroll
        for (int j = 0; j < 8; ++j) v[j] += p[lane + 64 * j];
        p += d.pstride;
    }
    float s1v = 0.f, s2v = 0.f;
#pragma unroll
    for (int j = 0; j < 8; ++j) { s1v += v[j]; s2v += v[j] * v[j]; }
#pragma unroll
    for (int off = 32; off; off >>= 1) {
        s1v += __shfl_xor(s1v, off, 64);
        s2v += __shfl_xor(s2v, off, 64);
    }
    const float mean = s1v * (1.0f / DIM);
    const float var = s2v * (1.0f / DIM) - mean * mean;
    const float rstd = rsqrtf(var + 1e-5f);
    ushort_t* q = d.d + (size_t)row * DIM;
#pragma unroll
    for (int j = 0; j < 8; ++j) {
        const int c = lane + 64 * j;
        float y = (v[j] - mean) * rstd * d.g[c] + d.b[c];
        q[c] = f2bf(fminf(fmaxf(y, 0.0f), 6.0f));
    }
}

// ---------------------------------------------------------------------------
// vplus = v + dwconv3x3 + bias, both branches in one launch
// ---------------------------------------------------------------------------
__device__ __forceinline__ void vplus_body(
    const ushort_t* __restrict__ vbuf, const float* __restrict__ lw,
    const float* __restrict__ lb, ushort_t* __restrict__ out,
    int lOW, int lL, int blk)
{
    const int idx = blk * 256 + threadIdx.x;
    const int c = idx & 255;
    const int pix = (idx >> 8) & ((1 << lL) - 1);
    const int b = idx >> (8 + lL);
    const int OW = 1 << lOW;
    const int y = pix >> lOW, x = pix & (OW - 1);
    float acc = lb[c];
#pragma unroll
    for (int dy = -1; dy <= 1; ++dy) {
        const int ny = y + dy;
        if ((unsigned)ny >= (unsigned)OW) continue;
#pragma unroll
        for (int dx = -1; dx <= 1; ++dx) {
            const int nx = x + dx;
            if ((unsigned)nx >= (unsigned)OW) continue;
            acc += bf2f(vbuf[(((unsigned)(b << lL) + ny * OW + nx) << 8) + c]) *
                   lw[c * 9 + (dy + 1) * 3 + (dx + 1)];
        }
    }
    out[idx] = f2bf(bf2f(vbuf[idx]) + acc);
}

__global__ __launch_bounds__(256) void vplus2_kernel(
    const ushort_t* v1, const float* w1, const float* b1, ushort_t* o1,
    const ushort_t* v2, const float* w2, const float* b2, ushort_t* o2)
{
    const int bid = blockIdx.x;
    if (bid < 2048) vplus_body(v1, w1, b1, o1, 4, 8, bid);
    else            vplus_body(v2, w2, b2, o2, 5, 10, bid - 2048);
}

// ---------------------------------------------------------------------------
// MFMA attention, all operands bf16 (Q pre-scaled by 0.125 in q-projection).
// Both branches merged into one launch: grid z in [0,8) = branch1 (L=256),
// [8,16) = branch2 (L=1024). Static 77,888B LDS (2 blocks/CU).
// WAVE-PRIVATE K/V staging (round-12, verified): phases A and C barrier-free
// via same-wave DS ordering. [round-19 setprio: regressed; reverted.]
// ---------------------------------------------------------------------------
template <int L>
__device__ __forceinline__ void attn_body(
    char* smem,
    const ushort_t* __restrict__ qbuf, const ushort_t* __restrict__ kbuf,
    const ushort_t* __restrict__ vbuf, ushort_t* __restrict__ xbuf,
    const int hoff, const int coff, const int b)
{
    constexpr int SP = L + 12;
    constexpr int NV = L / 64;
    float (*S)[SP]   = (float (*)[SP])smem;                       // 16*SP*4 B
    float* invs      = (float*)(smem + 64 * SP);                  // 64 B
    short (*Qs)[72]  = (short (*)[72])(smem + 64 * SP + 64);      // 2304 B
    short (*KV)[72]  = (short (*)[72])(smem + 64 * SP + 64 + 2304); // 9216 B

    const int tid = threadIdx.x;
    const int qt = blockIdx.x;
    const int h = blockIdx.y;
    const int lane = tid & 63, wave = tid >> 6;
    const int l16 = lane & 15, quad = lane >> 4;

    {
        const int r = tid >> 4, d0 = (tid & 15) * 4;
        int qi = qt * 16 + r; if (qi > QN - 1) qi = QN - 1;
        *(s16x4*)&Qs[r][d0] = *(const s16x4*)(
            qbuf + ((unsigned)(b * QN + qi) * NHEAD + hoff + h) * HD + d0);
    }
    __syncthreads();   // publish Qs (phase A itself needs no barriers)

    // Q fragments are loop-invariant: hoist once.
    s16x8 qf[2];
#pragma unroll
    for (int c = 0; c < 2; ++c)
        qf[c] = *(const s16x8*)&Qs[l16][c * 32 + quad * 8];

    // ---- Phase A: S = Q K^T ---- (KV rows wave-private; no barriers)
    const int klr = tid >> 2, kd0 = (tid & 3) * 16;
    for (int l0 = 0; l0 < L; l0 += 64) {
        const unsigned src = (unsigned)(b * L + l0 + klr) * C2 + h * HD + kd0;
        const s16x8 x0 = *(const s16x8*)(kbuf + src);
        const s16x8 x1 = *(const s16x8*)(kbuf + src + 8);
        *(s16x8*)&KV[klr][kd0] = x0;
        *(s16x8*)&KV[klr][kd0 + 8] = x1;
        f32x4 sacc = (f32x4){0.f, 0.f, 0.f, 0.f};
#pragma unroll
        for (int c = 0; c < 2; ++c) {
            const s16x8 bf = *(const s16x8*)&KV[wave * 16 + l16][c * 32 + quad * 8];
            sacc = __builtin_amdgcn_mfma_f32_16x16x32_bf16(qf[c], bf, sacc, 0, 0, 0);
        }
        const int col = l0 + wave * 16 + l16;
#pragma unroll
        for (int r = 0; r < 4; ++r) S[quad * 4 + r][col] = sacc[r];
    }
    __syncthreads();   // publish S for softmax

    // ---- Phase B: softmax ---- (rows wave-private)
#pragma unroll
    for (int rr = 0; rr < 4; ++rr) {
        const int row = wave * 4 + rr;
        float v[NV];
#pragma unroll
        for (int k = 0; k < NV; ++k) v[k] = S[row][lane + 64 * k];
        float m = -1e30f;
#pragma unroll
        for (int k = 0; k < NV; ++k) m = fmaxf(m, v[k]);
#pragma unroll
        for (int off = 32; off; off >>= 1) m = fmaxf(m, __shfl_xor(m, off, 64));
        float s = 0.f;
#pragma unroll
        for (int k = 0; k < NV; ++k) {
            v[k] = __expf(v[k] - m);
            s += v[k];
        }
#pragma unroll
        for (int off = 32; off; off >>= 1) s += __shfl_xor(s, off, 64);
#pragma unroll
        for (int k = 0; k < NV; ++k) S[row][lane + 64 * k] = v[k];
        if (lane == 0) invs[row] = 1.0f / s;
    }
    __syncthreads();   // publish softmax'd S + invs before PV

    // ---- Phase C: O = P V ---- (KV channel rows wave-private; no barriers)
    f32x4 oacc = (f32x4){0.f, 0.f, 0.f, 0.f};
    const int ctok = lane >> 2;                   // 0..15
    const int cd0 = wave * 16 + (lane & 3) * 4;   // wave-private channel base
    for (int l0 = 0; l0 < L; l0 += 64) {
#pragma unroll
        for (int p = 0; p < 4; ++p) {
            const int token = p * 16 + ctok;
            const s16x4 v = *(const s16x4*)(
                vbuf + (unsigned)(b * L + l0 + token) * C2 + h * HD + cd0);
            KV[cd0 + 0][token] = v[0];
            KV[cd0 + 1][token] = v[1];
            KV[cd0 + 2][token] = v[2];
            KV[cd0 + 3][token] = v[3];
        }
#pragma unroll
        for (int c = 0; c < 2; ++c) {
            const float4 p0 = *(const float4*)&S[l16][l0 + c * 32 + quad * 8];
            const float4 p1 = *(const float4*)&S[l16][l0 + c * 32 + quad * 8 + 4];
            const s16x8 af = pack8(p0, p1);
            const s16x8 bf = *(const s16x8*)&KV[wave * 16 + l16][c * 32 + quad * 8];
            oacc = __builtin_amdgcn_mfma_f32_16x16x32_bf16(af, bf, oacc, 0, 0, 0);
        }
    }

    const int dcol = wave * 16 + l16;
#pragma unroll
    for (int r = 0; r < 4; ++r) {
        const int q = quad * 4 + r;
        const int qi = qt * 16 + q;
        if (qi < QN) {
            const float val = oacc[r] * invs[q];
            const int flat = ((b * QN + qi) * NH2 + h) * HD + dcol;
            xbuf[(unsigned)(flat >> 8) * DIM + coff + (flat & 255)] = f2bf(val);
        }
    }
}

__global__ __launch_bounds__(256) void attn_both(
    const ushort_t* __restrict__ qbuf,
    const ushort_t* __restrict__ k1, const ushort_t* __restrict__ vp1,
    const ushort_t* __restrict__ k2, const ushort_t* __restrict__ vp2,
    ushort_t* __restrict__ xbuf)
{
    __shared__ char smem[77888] __attribute__((aligned(16)));
    const int bz = blockIdx.z;
    if (bz < 8) attn_body<256>(smem, qbuf, k1, vp1, xbuf, 0, 0, bz);
    else        attn_body<1024>(smem, qbuf, k2, vp2, xbuf, 4, 256, bz - 8);
}

// ---------------------------------------------------------------------------
// Launcher
// ---------------------------------------------------------------------------
extern "C" void kernel_launch(void* const* d_in, const int* in_sizes, int n_in,
                              void* d_out, int out_size, void* d_ws, size_t ws_size,
                              hipStream_t stream)
{
    const float* query   = (const float*)d_in[0];
    const float* key     = (const float*)d_in[1];
    const float* value   = (const float*)d_in[2];
    const float* q_w     = (const float*)d_in[3];
    const float* sr1_1_w = (const float*)d_in[4];
    const float* sr1_1_b = (const float*)d_in[5];
    const float* n1_1_g  = (const float*)d_in[6];
    const float* n1_1_b  = (const float*)d_in[7];
    const float* sr1_2_w = (const float*)d_in[8];
    const float* sr1_2_b = (const float*)d_in[9];
    const float* n1_2_g  = (const float*)d_in[10];
    const float* n1_2_b  = (const float*)d_in[11];
    const float* sr2_1_w = (const float*)d_in[12];
    const float* sr2_1_b = (const float*)d_in[13];
    const float* n2_1_g  = (const float*)d_in[14];
    const float* n2_1_b  = (const float*)d_in[15];
    const float* sr2_2_w = (const float*)d_in[16];
    const float* sr2_2_b = (const float*)d_in[17];
    const float* n2_2_g  = (const float*)d_in[18];
    const float* n2_2_b  = (const float*)d_in[19];
    const float* k1_w    = (const float*)d_in[20];
    const float* v1_w    = (const float*)d_in[21];
    const float* k2_w    = (const float*)d_in[22];
    const float* v2_w    = (const float*)d_in[23];
    const float* lc1_w   = (const float*)d_in[24];
    const float* lc1_b   = (const float*)d_in[25];
    const float* lc2_w   = (const float*)d_in[26];
    const float* lc2_b   = (const float*)d_in[27];
    const float* proj_w  = (const float*)d_in[28];
    const float* proj_b  = (const float*)d_in[29];
    float* out = (float*)d_out;
    char* ws = (char*)d_ws;

    // --- workspace layout (bytes); total ~199 MB (d_ws is 256 MiB) ---
    ushort_t* IMGK  = (ushort_t*)(ws + 0);            // 33.5 MB
    ushort_t* IMGV  = (ushort_t*)(ws + 33554432);     // 33.5 MB
    float*    SCRK1 = (float*)(ws + 67108864);        // 8.4 MB fp32 partials (z=2)
    float*    SCRV1 = (float*)(ws + 83886080);        // 8.4 MB
    float*    SCRK2 = (float*)(ws + 100663296);       // 16.8 MB
    float*    SCRV2 = (float*)(ws + 117440512);       // 16.8 MB
    ushort_t* WT1K  = (ushort_t*)(ws + 134217728);    // 8.4 MB
    ushort_t* WT1V  = (ushort_t*)(ws + 142606336);    // 8.4 MB
    ushort_t* WT2K  = (ushort_t*)(ws + 150994944);    // 2.1 MB
    ushort_t* WT2V  = (ushort_t*)(ws + 153092096);    // 2.1 MB
    ushort_t* KEY1  = (ushort_t*)(ws + 155189248);    // 2.1 MB
    ushort_t* VAL1  = (ushort_t*)(ws + 157286400);
    ushort_t* KEY2  = (ushort_t*)(ws + 159383552);    // 8.4 MB
    ushort_t* VAL2  = (ushort_t*)(ws + 167772160);
    ushort_t* QRYB  = (ushort_t*)(ws + 176160768);    // 1600x512 bf16
    ushort_t* WQ    = (ushort_t*)(ws + 177799168);
    ushort_t* WK1   = (ushort_t*)(ws + 178323456);
    ushort_t* WV1   = (ushort_t*)(ws + 178585600);
    ushort_t* WK2   = (ushort_t*)(ws + 178847744);
    ushort_t* WV2   = (ushort_t*)(ws + 179109888);
    ushort_t* WP    = (ushort_t*)(ws + 179372032);
    ushort_t* QBUF  = (ushort_t*)(ws + 179896320);
    ushort_t* XBUF  = (ushort_t*)(ws + 181534720);
    ushort_t* K1    = (ushort_t*)(ws + 183173120);
    ushort_t* V1    = (ushort_t*)(ws + 184221696);
    ushort_t* VP1   = (ushort_t*)(ws + 185270272);
    ushort_t* K2    = (ushort_t*)(ws + 186318848);
    ushort_t* V2    = (ushort_t*)(ws + 190513152);
    ushort_t* VP2   = (ushort_t*)(ws + 194707456);    // ends 198,901,760

    // 1) all fp32->bf16 conversions + conv-weight transposes (one launch)
    CPack cp;
    cp.c[0] = {key,   IMGK}; cp.c[1] = {value, IMGV}; cp.c[2] = {query, QRYB};
    cp.c[3] = {q_w,   WQ};   cp.c[4] = {k1_w,  WK1};  cp.c[5] = {v1_w,  WV1};
    cp.c[6] = {k2_w,  WK2};  cp.c[7] = {v2_w,  WV2};  cp.c[8] = {proj_w, WP};
    cp.bound[0] = 8192;  cp.bound[1] = 16384; cp.bound[2] = 16784;
    cp.bound[3] = 16912; cp.bound[4] = 16976; cp.bound[5] = 17040;
    cp.bound[6] = 17104; cp.bound[7] = 17168; cp.bound[8] = 17296;
    WPack wp;
    wp.w[0] = {sr1_1_w, WT1K, 16, 4}; wp.w[1] = {sr1_2_w, WT1V, 16, 4};
    wp.w[2] = {sr2_1_w, WT2K, 4, 2};  wp.w[3] = {sr2_2_w, WT2V, 4, 2};
    cvt_wtrans<<<19344, 256, 0, stream>>>(cp, wp);

    // 2) all 4 conv GEMMs in one launch:
    //    conv1: split-K z=2 (klen=4096, nk=64), 128 blocks/job
    //    conv2: z=1 (klen=2048, nk=32), 256 blocks/job
    GPack gp;
    gp.g[0] = {IMGK, WT1K, SCRK1, 2048, 8192, 4, 2, 4, 12, 64};
    gp.g[1] = {IMGV, WT1V, SCRV1, 2048, 8192, 4, 2, 4, 12, 64};
    gp.g[2] = {IMGK, WT2K, SCRK2, 8192, 2048, 5, 1, 6, 11, 32};
    gp.g[3] = {IMGV, WT2V, SCRV2, 8192, 2048, 5, 1, 6, 11, 32};
    gp.bound[0] = 128; gp.bound[1] = 256; gp.bound[2] = 512; gp.bound[3] = 768;
    conv_gemm<<<768, 256, 0, stream>>>(gp);

    // 3) all 4 LN+ReLU6 (+split-K reduce + conv bias) in one launch
    LPack lp;
    lp.l[0] = {KEY1, SCRK1, sr1_1_b, n1_1_g, n1_1_b, 1048576u, 2};
    lp.l[1] = {VAL1, SCRV1, sr1_2_b, n1_2_g, n1_2_b, 1048576u, 2};
    lp.l[2] = {KEY2, SCRK2, sr2_1_b, n2_1_g, n2_1_b, 4194304u, 1};
    lp.l[3] = {VAL2, SCRV2, sr2_2_b, n2_2_g, n2_2_b, 4194304u, 1};
    lp.bound[0] = 512; lp.bound[1] = 1024; lp.bound[2] = 3072; lp.bound[3] = 5120;
    ln_all<<<5120, 256, 0, stream>>>(lp);

    // 4) merged projections: q (scale 0.125 folded), k1, v1, k2, v2
    PPack pp;
    pp.d[0] = {QRYB, WQ,  QBUF, 3, 0.125f};
    pp.d[1] = {KEY1, WK1, K1,   2, 1.0f};
    pp.d[2] = {VAL1, WV1, V1,   2, 1.0f};
    pp.d[3] = {KEY2, WK2, K2,   2, 1.0f};
    pp.d[4] = {VAL2, WV2, V2,   2, 1.0f};
    pp.bound[0] = 200; pp.bound[1] = 328; pp.bound[2] = 456; pp.bound[3] = 968;
    pp.bound[4] = 1480;
    proj_gemm<<<1480, 256, 0, stream>>>(pp);

    // 5) v + local dwconv (both branches)
    vplus2_kernel<<<10240, 256, 0, stream>>>(V1, lc1_w, lc1_b, VP1,
                                             V2, lc2_w, lc2_b, VP2);

    // 6) attention, both branches in one launch (co-resident)
    attn_both<<<dim3(13, 4, 16), 256, 0, stream>>>(QBUF, K1, VP1, K2, VP2, XBUF);

    // 7) final projection + bias -> fp32 out
    final_gemm<<<200, 256, 0, stream>>>(XBUF, WP, proj_b, out);
}